// Round 1
// baseline (1132.744 us; speedup 1.0000x reference)
//
#include <hip/hip_runtime.h>
#include <cmath>
#include <cstdint>

// HashPINN R10:
//  - featT now stores PRE-SPLIT bf16 hi/lo pairs per (level,point):
//    {hi0|hi1<<16, lo0|lo1<<16} (8B, same traffic as f32 v2f). hi = truncated
//    bf16, lo = RNE bf16 of exact remainder -> bit-identical to the old
//    in-MLP split8. Encode is memory-bound; the split VALU there is free.
//  - mlp_mfma rewritten: weights are the A operand, features/activations the
//    B operand, so C = [neuron][point] with col=point=lane&15. Inter-layer
//    transpose becomes a fixed 2-source-lane register exchange (ds_bpermute
//    via __shfl) + quad-select; LDS is eliminated entirely (was 33 KB/block,
//    capping occupancy at 50%, with ~4-way bank conflicts = 1.6e7 cyc).
//    Biases/Wo consumed as per-reg v4f (row = quad*4+r). Epilogue stores are
//    full-16-lane coalesced. launch_bounds(256,6) -> 24 waves/CU.
//  - Encode: unchanged R7/R9 gather structure ((256,8), grid 4096, paired
//    even/odd hash loads). Hashed levels are at the per-CU outstanding-miss
//    wall (~55 concurrent line misses/CU); untouched this round.

#define HASH_SZ (1u << 19)
#define HMASK   (HASH_SZ - 1u)
#define PR2 2654435761u
#define PR3 805459861u

typedef float v2f __attribute__((ext_vector_type(2)));
typedef float v4f __attribute__((ext_vector_type(4)));
typedef v4f v4fu __attribute__((aligned(8)));
typedef v2f v2fu __attribute__((aligned(8)));
typedef short bf16x8 __attribute__((ext_vector_type(8)));
typedef float f32x4 __attribute__((ext_vector_type(4)));
typedef unsigned int u32;
typedef u32 u32x2 __attribute__((ext_vector_type(2)));
typedef u32 u32x4 __attribute__((ext_vector_type(4)));

struct ResArr { int r[16]; };

// ---------- bf16 helpers ----------
__device__ __forceinline__ unsigned short bf16_rne(float f) {
    union { float f; unsigned u; } v; v.f = f;
    unsigned u = v.u;
    unsigned r = (u + 0x7fffu + ((u >> 16) & 1u)) >> 16;
    return (unsigned short)r;
}
__device__ __forceinline__ float bf16f(unsigned short h) {
    union { unsigned u; float f; } v; v.u = ((unsigned)h) << 16;
    return v.f;
}
// hi = TRUNCATED bf16 (cheap); lo = RNE bf16 of the exact remainder.
__device__ __forceinline__ void split8(const float* x, bf16x8& hi, bf16x8& lo) {
    #pragma unroll
    for (int j = 0; j < 8; ++j) {
        union { float f; unsigned u; } v; v.f = x[j];
        const unsigned hu = v.u & 0xffff0000u;
        hi[j] = (short)(hu >> 16);
        union { unsigned u; float f; } hf; hf.u = hu;
        const float d = x[j] - hf.f;
        union { float f; unsigned u; } dv; dv.f = d;
        lo[j] = (short)((dv.u + 0x7fffu + ((dv.u >> 16) & 1u)) >> 16);
    }
}
__device__ __forceinline__ u32 rne16u(float f) {
    union { float f; u32 u; } v; v.f = f;
    return (v.u + 0x7fffu + ((v.u >> 16) & 1u)) >> 16;
}
// pack two features into {hi0|hi1<<16, lo0|lo1<<16} (bit-identical to split8)
__device__ __forceinline__ u32x2 pack_split2(float f0, float f1) {
    union { float f; u32 u; } a, b; a.f = f0; b.f = f1;
    const u32 h0 = a.u & 0xffff0000u, h1 = b.u & 0xffff0000u;
    union { u32 u; float f; } ha, hb; ha.u = h0; hb.u = h1;
    u32x2 r;
    r.x = (h0 >> 16) | h1;
    r.y = rne16u(f0 - ha.f) | (rne16u(f1 - hb.f) << 16);
    return r;
}

// ---------------- encode (R7 gather, (256,8)) ----------------
__device__ __forceinline__ void gather_one(
    const v2f* __restrict__ tbl, int res, bool dense,
    float px, float py, float pz, float& A0, float& A1)
{
    const float rf = (float)(res - 1);
    const float fx = px * rf, fy = py * rf, fz = pz * rf;
    int ix = (int)floorf(fx), iy = (int)floorf(fy), iz = (int)floorf(fz);
    ix = min(max(ix, 0), res - 2);
    iy = min(max(iy, 0), res - 2);
    iz = min(max(iz, 0), res - 2);
    const float tx = fx - (float)ix, ty = fy - (float)iy, tz = fz - (float)iz;
    const float sx = 1.f - tx, sy = 1.f - ty, sz = 1.f - tz;
    float a0 = 0.f, a1 = 0.f;

    if (dense) {
        const int b0 = ix + res * (iy + res * iz);
        v4fu P[4];
        #pragma unroll
        for (int c = 0; c < 4; ++c) {
            const int dy = c >> 1, dz = c & 1;
            P[c] = *(const v4fu*)((const float*)tbl + 2 * (b0 + res * dy + res * res * dz));
        }
        #pragma unroll
        for (int c = 0; c < 4; ++c) {
            const int dy = c >> 1, dz = c & 1;
            const float wyz = (dy ? ty : sy) * (dz ? tz : sz);
            const float w0 = sx * wyz, w1 = tx * wyz;
            a0 = fmaf(w0, P[c].x, a0); a1 = fmaf(w0, P[c].y, a1);
            a0 = fmaf(w1, P[c].z, a0); a1 = fmaf(w1, P[c].w, a1);
        }
    } else {
        uint32_t i0[4], i1[4];
        v4f P[4];
        #pragma unroll
        for (int c = 0; c < 4; ++c) {
            const int dy = c >> 1, dz = c & 1;
            const uint32_t r = (uint32_t)(iy + dy) * PR2 ^ (uint32_t)(iz + dz) * PR3;
            i0[c] = ((uint32_t)ix ^ r) & HMASK;
            i1[c] = ((uint32_t)(ix + 1) ^ r) & HMASK;
            P[c] = *(const v4f*)((const float*)tbl + 2 * (i0[c] & ~1u));
        }
        const bool odd = (ix & 1);
        v2f O[4];
        if (odd) {
            #pragma unroll
            for (int c = 0; c < 4; ++c) O[c] = tbl[i1[c]];
        } else {
            #pragma unroll
            for (int c = 0; c < 4; ++c) { v2f z = {0.f, 0.f}; O[c] = z; }
        }
        #pragma unroll
        for (int c = 0; c < 4; ++c) {
            const int dy = c >> 1, dz = c & 1;
            const bool hi = (i0[c] & 1);
            v2f c0, e;
            c0.x = hi ? P[c].z : P[c].x;  c0.y = hi ? P[c].w : P[c].y;
            e.x  = hi ? P[c].x : P[c].z;  e.y  = hi ? P[c].y : P[c].w;
            const v2f c1 = odd ? O[c] : e;
            const float wyz = (dy ? ty : sy) * (dz ? tz : sz);
            const float w0 = sx * wyz, w1 = tx * wyz;
            a0 = fmaf(w0, c0.x, a0); a1 = fmaf(w0, c0.y, a1);
            a0 = fmaf(w1, c1.x, a0); a1 = fmaf(w1, c1.y, a1);
        }
    }
    A0 = a0; A1 = a1;
}

template<int NLEV>
__global__ __launch_bounds__(256, 8)
void encode_k(const float* __restrict__ x, const float* __restrict__ table,
              u32x2* __restrict__ featT, int n, int lb, ResArr rv)
{
    const int nth2 = gridDim.x * 512;
    for (int q = (blockIdx.x * 256 + threadIdx.x) * 2; q < n; q += nth2) {
        float p0x, p0y, p0z, p1x, p1y, p1z;
        const bool two = (q + 1 < n);
        if (two) {
            const v4fu a = __builtin_nontemporal_load((const v4fu*)(x + 3 * q));
            const v2f  b = __builtin_nontemporal_load((const v2fu*)(x + 3 * q + 4));
            p0x = a.x; p0y = a.y; p0z = a.z; p1x = a.w; p1y = b.x; p1z = b.y;
        } else {
            p0x = x[3 * q]; p0y = x[3 * q + 1]; p0z = x[3 * q + 2];
            p1x = p0x; p1y = p0y; p1z = p0z;
        }
        #pragma unroll
        for (int il = 0; il < NLEV; ++il) {
            const int l = lb + il;
            const int res = rv.r[l];
            const bool dense = ((long long)res * res * res <= (long long)HASH_SZ);
            const v2f* tbl = (const v2f*)table + (size_t)l * HASH_SZ;
            float a00, a01, a10, a11;
            gather_one(tbl, res, dense, p0x, p0y, p0z, a00, a01);
            gather_one(tbl, res, dense, p1x, p1y, p1z, a10, a11);
            if (two) {
                const u32x2 e0 = pack_split2(a00, a01);
                const u32x2 e1 = pack_split2(a10, a11);
                u32x4 st; st.x = e0.x; st.y = e0.y; st.z = e1.x; st.w = e1.y;
                __builtin_nontemporal_store(st, (u32x4*)&featT[(size_t)l * n + q]);
            } else {
                __builtin_nontemporal_store(pack_split2(a00, a01),
                                            &featT[(size_t)l * n + q]);
            }
        }
    }
}

// ---------------- weight prep (layout doubles as A-operand frags) ----------------
__global__ void prep_weights(const float* __restrict__ W1,
                             const float* __restrict__ W2,
                             const float* __restrict__ W3,
                             unsigned short* __restrict__ wb)
{
    const int tid = threadIdx.x;
    const int nb = tid >> 6, lane = tid & 63;
    const int l15 = lane & 15, q = lane >> 4;
    #pragma unroll
    for (int j = 0; j < 8; ++j) {
        const float v = W1[(q * 8 + j) * 64 + nb * 16 + l15];
        const unsigned short h = bf16_rne(v);
        wb[(nb * 64 + lane) * 8 + j] = h;
        wb[2048 + (nb * 64 + lane) * 8 + j] = bf16_rne(v - bf16f(h));
    }
    #pragma unroll
    for (int kb = 0; kb < 2; ++kb) {
        #pragma unroll
        for (int j = 0; j < 8; ++j) {
            const int row = kb * 32 + q * 8 + j;
            const int idx = ((kb * 4 + nb) * 64 + lane) * 8 + j;
            float v = W2[row * 64 + nb * 16 + l15];
            unsigned short h = bf16_rne(v);
            wb[4096 + idx] = h;
            wb[8192 + idx] = bf16_rne(v - bf16f(h));
            v = W3[row * 64 + nb * 16 + l15];
            h = bf16_rne(v);
            wb[12288 + idx] = h;
            wb[16384 + idx] = bf16_rne(v - bf16f(h));
        }
    }
}

// ---------------- MFMA MLP: weights=A, acts=B, no LDS ----------------
__global__ __launch_bounds__(256, 6)
void mlp_mfma(const u32x2* __restrict__ featT,
              const unsigned short* __restrict__ wb,
              const float* __restrict__ b1, const float* __restrict__ b2,
              const float* __restrict__ b3,
              const float* __restrict__ Wo, const float* __restrict__ bo,
              float* __restrict__ out, int n)
{
    const int wave = threadIdx.x >> 6;
    const int lane = threadIdx.x & 63;
    const int l15 = lane & 15, quad = lane >> 4;
    const int p0 = (blockIdx.x * 4 + wave) * 32;
    if (p0 >= n) return;

    // inter-layer exchange: target (quad,l15) pulls neurons m=32kb+8*quad+j.
    // j=0..3 from lane s0 = ((2q)&3)*16+l15, j=4..7 from s1 = ((2q+1)&3)*16+l15,
    // reg = j&3, source array nb = 2kb + (quad>>1) (select hiHalf).
    const int s0 = (((2 * quad) & 3) << 4) + l15;
    const int s1 = (((2 * quad + 1) & 3) << 4) + l15;
    const bool hiHalf = (quad >= 2);

    // ---- layer 1: B-frags straight from pre-split featT ----
    bf16x8 bh[2], bl[2];
    #pragma unroll
    for (int t = 0; t < 2; ++t) {
        const int p = p0 + t * 16 + l15;
        const int pl = (p < n) ? p : (n - 1);
        u32x4 hw, lw;
        #pragma unroll
        for (int jj = 0; jj < 4; ++jj) {
            const u32x2 v = featT[(size_t)(quad * 4 + jj) * n + pl];
            hw[jj] = v.x; lw[jj] = v.y;
        }
        bh[t] = *(bf16x8*)&hw;
        bl[t] = *(bf16x8*)&lw;
    }

    f32x4 acc[2][4];
    #pragma unroll
    for (int nb = 0; nb < 4; ++nb) {
        const bf16x8 wh = *(const bf16x8*)(wb + (nb * 64 + lane) * 8);
        const bf16x8 wl = *(const bf16x8*)(wb + 2048 + (nb * 64 + lane) * 8);
        const f32x4 bv = *(const f32x4*)(b1 + nb * 16 + quad * 4);
        #pragma unroll
        for (int t = 0; t < 2; ++t) {
            f32x4 c = bv;
            c = __builtin_amdgcn_mfma_f32_16x16x32_bf16(wh, bl[t], c, 0, 0, 0);
            c = __builtin_amdgcn_mfma_f32_16x16x32_bf16(wl, bh[t], c, 0, 0, 0);
            c = __builtin_amdgcn_mfma_f32_16x16x32_bf16(wh, bh[t], c, 0, 0, 0);
            acc[t][nb] = c;
        }
    }

    // ---- hidden layers 2 & 3 ----
    #pragma unroll
    for (int layer = 0; layer < 2; ++layer) {
        bf16x8 nh[2][2], nl[2][2];
        #pragma unroll
        for (int t = 0; t < 2; ++t) {
            #pragma unroll
            for (int kb = 0; kb < 2; ++kb) {
                float v[8];
                #pragma unroll
                for (int j = 0; j < 4; ++j) {
                    const float a0 = __shfl(acc[t][2 * kb][j],     s0, 64);
                    const float a1 = __shfl(acc[t][2 * kb + 1][j], s0, 64);
                    const float c0 = __shfl(acc[t][2 * kb][j],     s1, 64);
                    const float c1 = __shfl(acc[t][2 * kb + 1][j], s1, 64);
                    v[j]     = fmaxf(hiHalf ? a1 : a0, 0.f);
                    v[4 + j] = fmaxf(hiHalf ? c1 : c0, 0.f);
                }
                split8(v, nh[t][kb], nl[t][kb]);
            }
        }
        const int base_h = layer ? 12288 : 4096;
        const int base_l = layer ? 16384 : 8192;
        const float* __restrict__ bias = layer ? b3 : b2;
        #pragma unroll
        for (int nb = 0; nb < 4; ++nb) {
            const f32x4 bv = *(const f32x4*)(bias + nb * 16 + quad * 4);
            f32x4 c[2];
            #pragma unroll
            for (int t = 0; t < 2; ++t) c[t] = bv;
            #pragma unroll
            for (int kb = 0; kb < 2; ++kb) {
                const int idx = ((kb * 4 + nb) * 64 + lane) * 8;
                const bf16x8 wh = *(const bf16x8*)(wb + base_h + idx);
                const bf16x8 wl = *(const bf16x8*)(wb + base_l + idx);
                #pragma unroll
                for (int t = 0; t < 2; ++t) {
                    c[t] = __builtin_amdgcn_mfma_f32_16x16x32_bf16(wh, nl[t][kb], c[t], 0, 0, 0);
                    c[t] = __builtin_amdgcn_mfma_f32_16x16x32_bf16(wl, nh[t][kb], c[t], 0, 0, 0);
                    c[t] = __builtin_amdgcn_mfma_f32_16x16x32_bf16(wh, nh[t][kb], c[t], 0, 0, 0);
                }
            }
            #pragma unroll
            for (int t = 0; t < 2; ++t) acc[t][nb] = c[t];
        }
    }

    // ---- output layer: lane holds 16 neurons of point l15; quad-reduce ----
    float part[2];
    #pragma unroll
    for (int t = 0; t < 2; ++t) {
        float s = 0.f;
        #pragma unroll
        for (int nb = 0; nb < 4; ++nb) {
            const f32x4 wo4 = *(const f32x4*)(Wo + nb * 16 + quad * 4);
            #pragma unroll
            for (int r = 0; r < 4; ++r)
                s = fmaf(fmaxf(acc[t][nb][r], 0.f), wo4[r], s);
        }
        part[t] = s;
    }
    #pragma unroll
    for (int t = 0; t < 2; ++t) {
        part[t] += __shfl_xor(part[t], 16, 64);
        part[t] += __shfl_xor(part[t], 32, 64);
    }
    if (quad == 0) {
        const float b = bo[0];
        #pragma unroll
        for (int t = 0; t < 2; ++t) {
            const int po = p0 + t * 16 + l15;
            if (po < n) out[po] = part[t] + b;
        }
    }
}

// ---------------- fp32 MLP (ws-fallback path) ----------------
__global__ __launch_bounds__(256, 3)
void mlp_forward(const u32x2* __restrict__ featT,
                 const float* __restrict__ W1, const float* __restrict__ b1,
                 const float* __restrict__ W2, const float* __restrict__ b2,
                 const float* __restrict__ W3, const float* __restrict__ b3,
                 const float* __restrict__ Wo, const float* __restrict__ bo,
                 float* __restrict__ out, int n)
{
    const int p = blockIdx.x * 256 + threadIdx.x;
    if (p >= n) return;
    const v2f z2 = {0.f, 0.f};
    v2f A[32], B[32];
    #pragma unroll
    for (int jq = 0; jq < 16; ++jq) {
        const v4f b = *(const v4f*)(b1 + 4 * jq);
        A[2 * jq] = b.xy; A[2 * jq + 1] = b.zw;
    }
    #pragma unroll
    for (int l = 0; l < 16; ++l) {
        const u32x2 e = __builtin_nontemporal_load(&featT[(size_t)l * n + p]);
        union { u32 u; float f; } h0, h1, l0, l1;
        h0.u = e.x << 16; h1.u = e.x & 0xffff0000u;
        l0.u = e.y << 16; l1.u = e.y & 0xffff0000u;
        v2f f; f.x = h0.f + l0.f; f.y = h1.f + l1.f;
        const v4f* w0 = (const v4f*)(W1 + (size_t)(2 * l) * 64);
        const v4f* w1 = (const v4f*)(W1 + (size_t)(2 * l + 1) * 64);
        const v2f hh0 = {f.x, f.x}, hh1 = {f.y, f.y};
        #pragma unroll
        for (int jq = 0; jq < 16; ++jq) {
            const v4f wa = w0[jq];
            A[2 * jq]     = __builtin_elementwise_fma(hh0, wa.xy, A[2 * jq]);
            A[2 * jq + 1] = __builtin_elementwise_fma(hh0, wa.zw, A[2 * jq + 1]);
        }
        #pragma unroll
        for (int jq = 0; jq < 16; ++jq) {
            const v4f wb2 = w1[jq];
            A[2 * jq]     = __builtin_elementwise_fma(hh1, wb2.xy, A[2 * jq]);
            A[2 * jq + 1] = __builtin_elementwise_fma(hh1, wb2.zw, A[2 * jq + 1]);
        }
    }
    #pragma unroll
    for (int j = 0; j < 32; ++j) A[j] = __builtin_elementwise_max(A[j], z2);
    #pragma unroll
    for (int jq = 0; jq < 16; ++jq) {
        const v4f b = *(const v4f*)(b2 + 4 * jq);
        B[2 * jq] = b.xy; B[2 * jq + 1] = b.zw;
    }
    #pragma unroll
    for (int k = 0; k < 64; ++k) {
        const float hv = A[k >> 1][k & 1];
        const v2f h = {hv, hv};
        const v4f* w = (const v4f*)(W2 + (size_t)k * 64);
        #pragma unroll
        for (int jq = 0; jq < 16; ++jq) {
            const v4f wa = w[jq];
            B[2 * jq]     = __builtin_elementwise_fma(h, wa.xy, B[2 * jq]);
            B[2 * jq + 1] = __builtin_elementwise_fma(h, wa.zw, B[2 * jq + 1]);
        }
    }
    #pragma unroll
    for (int j = 0; j < 32; ++j) B[j] = __builtin_elementwise_max(B[j], z2);
    #pragma unroll
    for (int jq = 0; jq < 16; ++jq) {
        const v4f b = *(const v4f*)(b3 + 4 * jq);
        A[2 * jq] = b.xy; A[2 * jq + 1] = b.zw;
    }
    #pragma unroll
    for (int k = 0; k < 64; ++k) {
        const float hv = B[k >> 1][k & 1];
        const v2f h = {hv, hv};
        const v4f* w = (const v4f*)(W3 + (size_t)k * 64);
        #pragma unroll
        for (int jq = 0; jq < 16; ++jq) {
            const v4f wa = w[jq];
            A[2 * jq]     = __builtin_elementwise_fma(h, wa.xy, A[2 * jq]);
            A[2 * jq + 1] = __builtin_elementwise_fma(h, wa.zw, A[2 * jq + 1]);
        }
    }
    v2f o2 = z2;
    #pragma unroll
    for (int jq = 0; jq < 16; ++jq) {
        const v4f wa = *(const v4f*)(Wo + 4 * jq);
        o2 = __builtin_elementwise_fma(__builtin_elementwise_max(A[2 * jq], z2),     wa.xy, o2);
        o2 = __builtin_elementwise_fma(__builtin_elementwise_max(A[2 * jq + 1], z2), wa.zw, o2);
    }
    out[p] = o2.x + o2.y + bo[0];
}

// ---------------- fallback (ws too small): R1-style fused ----------------
__global__ __launch_bounds__(256, 2)
void hashpinn_fused(const float* __restrict__ x,
                    const float* __restrict__ table,
                    const float* __restrict__ W1, const float* __restrict__ b1,
                    const float* __restrict__ W2, const float* __restrict__ b2,
                    const float* __restrict__ W3, const float* __restrict__ b3,
                    const float* __restrict__ Wo, const float* __restrict__ bo,
                    float* __restrict__ out, int n, ResArr rv)
{
    const int p = blockIdx.x * 256 + threadIdx.x;
    if (p >= n) return;
    const float px = x[3*p+0], py = x[3*p+1], pz = x[3*p+2];
    float feat[32];
    #pragma unroll
    for (int l = 0; l < 16; ++l) {
        const int res = rv.r[l];
        const float rf = (float)(res - 1);
        const float fx = px*rf, fy = py*rf, fz = pz*rf;
        int ix=(int)floorf(fx), iy=(int)floorf(fy), iz=(int)floorf(fz);
        ix=min(max(ix,0),res-2); iy=min(max(iy,0),res-2); iz=min(max(iz,0),res-2);
        const float tx=fx-(float)ix, ty=fy-(float)iy, tz=fz-(float)iz;
        const float sx=1.f-tx, sy=1.f-ty, sz=1.f-tz;
        const float2* tbl=(const float2*)table+(size_t)l*HASH_SZ;
        const bool dense=((long long)res*res*res<=(long long)HASH_SZ);
        float a0=0.f, a1=0.f;
        #pragma unroll
        for (int c=0;c<8;++c){
            const uint32_t cx=(uint32_t)(ix+((c>>2)&1));
            const uint32_t cy=(uint32_t)(iy+((c>>1)&1));
            const uint32_t cz=(uint32_t)(iz+(c&1));
            uint32_t idx = dense ? cx+(uint32_t)res*(cy+(uint32_t)res*cz)
                                 : ((cx*1u ^ cy*PR2 ^ cz*PR3)&HMASK);
            const float2 v=tbl[idx];
            const float w=(((c>>2)&1)?tx:sx)*(((c>>1)&1)?ty:sy)*((c&1)?tz:sz);
            a0=fmaf(w,v.x,a0); a1=fmaf(w,v.y,a1);
        }
        feat[2*l]=a0; feat[2*l+1]=a1;
    }
    float A[64], B[64];
    #pragma unroll
    for (int j=0;j<64;++j) A[j]=b1[j];
    #pragma unroll
    for (int k=0;k<32;++k){ const float h=feat[k];
        #pragma unroll
        for (int j=0;j<64;++j) A[j]=fmaf(h,W1[k*64+j],A[j]); }
    #pragma unroll 1
    for (int it=0;it<2;++it){
        const float* W = it?W3:W2; const float* bb = it?b3:b2;
        #pragma unroll
        for (int j=0;j<64;++j){ A[j]=fmaxf(A[j],0.f); B[j]=bb[j]; }
        #pragma unroll
        for (int k=0;k<64;++k){ const float h=A[k];
            #pragma unroll
            for (int j=0;j<64;++j) B[j]=fmaf(h,W[k*64+j],B[j]); }
        #pragma unroll
        for (int j=0;j<64;++j) A[j]=B[j];
    }
    float o=bo[0];
    #pragma unroll
    for (int j=0;j<64;++j) o=fmaf(fmaxf(A[j],0.f),Wo[j],o);
    out[p]=o;
}

static inline void launch_encode(int nlev, const float* x, const float* table,
                                 u32x2* featT, int n, int lb, const ResArr& rv,
                                 hipStream_t stream) {
    const dim3 g(4096), b(256);
    switch (nlev) {
        case 1: hipLaunchKernelGGL(encode_k<1>, g, b, 0, stream, x, table, featT, n, lb, rv); break;
        case 2: hipLaunchKernelGGL(encode_k<2>, g, b, 0, stream, x, table, featT, n, lb, rv); break;
        case 3: hipLaunchKernelGGL(encode_k<3>, g, b, 0, stream, x, table, featT, n, lb, rv); break;
        case 4: hipLaunchKernelGGL(encode_k<4>, g, b, 0, stream, x, table, featT, n, lb, rv); break;
        case 5: hipLaunchKernelGGL(encode_k<5>, g, b, 0, stream, x, table, featT, n, lb, rv); break;
        case 6: hipLaunchKernelGGL(encode_k<6>, g, b, 0, stream, x, table, featT, n, lb, rv); break;
        case 7: hipLaunchKernelGGL(encode_k<7>, g, b, 0, stream, x, table, featT, n, lb, rv); break;
        default: hipLaunchKernelGGL(encode_k<8>, g, b, 0, stream, x, table, featT, n, lb, rv); break;
    }
}

extern "C" void kernel_launch(void* const* d_in, const int* in_sizes, int n_in,
                              void* d_out, int out_size, void* d_ws, size_t ws_size,
                              hipStream_t stream) {
    const float* x     = (const float*)d_in[0];
    const float* table = (const float*)d_in[1];
    const float* W1    = (const float*)d_in[2];
    const float* b1    = (const float*)d_in[3];
    const float* W2    = (const float*)d_in[4];
    const float* b2    = (const float*)d_in[5];
    const float* W3    = (const float*)d_in[6];
    const float* b3    = (const float*)d_in[7];
    const float* Wo    = (const float*)d_in[8];
    const float* bo    = (const float*)d_in[9];
    float* out = (float*)d_out;

    const int n = in_sizes[0] / 3;

    ResArr rv;
    const double scale = std::exp2(std::log2(2048.0 / 16.0) / 15.0);
    for (int l = 0; l < 16; ++l)
        rv.r[l] = (int)std::ceil(16.0 * std::pow(scale, (double)l));

    int dense_end = 0;
    while (dense_end < 16) {
        long long r = rv.r[dense_end];
        if (r * r * r <= (long long)HASH_SZ) ++dense_end; else break;
    }
    if (dense_end > 8) dense_end = 8;

    const size_t feat_bytes = (size_t)n * 16 * sizeof(u32x2);
    const size_t wb_bytes = 20480 * sizeof(unsigned short);

    if (ws_size >= feat_bytes + wb_bytes) {
        u32x2* featT = (u32x2*)d_ws;
        unsigned short* wb = (unsigned short*)((char*)d_ws + feat_bytes);

        hipLaunchKernelGGL(prep_weights, dim3(1), dim3(256), 0, stream, W1, W2, W3, wb);

        if (dense_end > 0)
            launch_encode(dense_end, x, table, featT, n, 0, rv, stream);
        for (int l = dense_end; l < 16; ++l)
            launch_encode(1, x, table, featT, n, l, rv, stream);

        const int nblocks = (n + 127) / 128;   // 128 pts/block (4 waves x 32)
        hipLaunchKernelGGL(mlp_mfma, dim3(nblocks), dim3(256), 0, stream,
                           featT, wb, b1, b2, b3, Wo, bo, out, n);
    } else if (ws_size >= feat_bytes) {
        u32x2* featT = (u32x2*)d_ws;
        if (dense_end > 0)
            launch_encode(dense_end, x, table, featT, n, 0, rv, stream);
        for (int l = dense_end; l < 16; ++l)
            launch_encode(1, x, table, featT, n, l, rv, stream);
        hipLaunchKernelGGL(mlp_forward, dim3((n + 255) / 256), dim3(256), 0, stream,
                           featT, W1, b1, W2, b2, W3, b3, Wo, bo, out, n);
    } else {
        hipLaunchKernelGGL(hashpinn_fused, dim3((n + 255) / 256), dim3(256), 0, stream,
                           x, table, W1, b1, W2, b2, W3, b3, Wo, bo, out, n, rv);
    }
}

// Round 3
// 1077.460 us; speedup vs baseline: 1.0513x; 1.0513x over previous
//
#include <hip/hip_runtime.h>
#include <cmath>
#include <cstdint>

// HashPINN R12:
//  - R11 permlane exchange had operand roles reversed. ISA semantics:
//    v_permlane32_swap_b32 vdst,vsrc: DST.row1(lanes32-63) <-> SRC.row0;
//    v_permlane16_swap_b32: DST 16-rows 1,3 <-> SRC 16-rows 0,2.
//    Correct sequence (verified against the R10-passing shfl mapping):
//      swap32(dst=x, src=y) -> x={xq0,xq1,yq0,yq1}, y={xq2,xq3,yq2,yq3}
//      swap16(dst=x, src=y) -> x={xq0,xq2,yq0,yq2}=v[r], y={xq1,xq3,yq1,yq3}=v[4+r]
//  - Rest unchanged from R11: (256,4) launch bound (R10's (256,6) caused
//    40-VGPR alloc -> 250MB scratch spill traffic), weights=A / acts=B
//    (no LDS), pre-split bf16 hi/lo featT.

#define HASH_SZ (1u << 19)
#define HMASK   (HASH_SZ - 1u)
#define PR2 2654435761u
#define PR3 805459861u

typedef float v2f __attribute__((ext_vector_type(2)));
typedef float v4f __attribute__((ext_vector_type(4)));
typedef v4f v4fu __attribute__((aligned(8)));
typedef v2f v2fu __attribute__((aligned(8)));
typedef short bf16x8 __attribute__((ext_vector_type(8)));
typedef float f32x4 __attribute__((ext_vector_type(4)));
typedef unsigned int u32;
typedef u32 u32x2 __attribute__((ext_vector_type(2)));
typedef u32 u32x4 __attribute__((ext_vector_type(4)));

struct ResArr { int r[16]; };

// ---------- bf16 helpers ----------
__device__ __forceinline__ unsigned short bf16_rne(float f) {
    union { float f; unsigned u; } v; v.f = f;
    unsigned u = v.u;
    unsigned r = (u + 0x7fffu + ((u >> 16) & 1u)) >> 16;
    return (unsigned short)r;
}
__device__ __forceinline__ float bf16f(unsigned short h) {
    union { unsigned u; float f; } v; v.u = ((unsigned)h) << 16;
    return v.f;
}
// hi = TRUNCATED bf16 (cheap); lo = RNE bf16 of the exact remainder.
__device__ __forceinline__ void split8(const float* x, bf16x8& hi, bf16x8& lo) {
    #pragma unroll
    for (int j = 0; j < 8; ++j) {
        union { float f; unsigned u; } v; v.f = x[j];
        const unsigned hu = v.u & 0xffff0000u;
        hi[j] = (short)(hu >> 16);
        union { unsigned u; float f; } hf; hf.u = hu;
        const float d = x[j] - hf.f;
        union { float f; unsigned u; } dv; dv.f = d;
        lo[j] = (short)((dv.u + 0x7fffu + ((dv.u >> 16) & 1u)) >> 16);
    }
}
__device__ __forceinline__ u32 rne16u(float f) {
    union { float f; u32 u; } v; v.f = f;
    return (v.u + 0x7fffu + ((v.u >> 16) & 1u)) >> 16;
}
// pack two features into {hi0|hi1<<16, lo0|lo1<<16} (bit-identical to split8)
__device__ __forceinline__ u32x2 pack_split2(float f0, float f1) {
    union { float f; u32 u; } a, b; a.f = f0; b.f = f1;
    const u32 h0 = a.u & 0xffff0000u, h1 = b.u & 0xffff0000u;
    union { u32 u; float f; } ha, hb; ha.u = h0; hb.u = h1;
    u32x2 r;
    r.x = (h0 >> 16) | h1;
    r.y = rne16u(f0 - ha.f) | (rne16u(f1 - hb.f) << 16);
    return r;
}

// ---------------- encode (R7 gather, (256,8)) ----------------
__device__ __forceinline__ void gather_one(
    const v2f* __restrict__ tbl, int res, bool dense,
    float px, float py, float pz, float& A0, float& A1)
{
    const float rf = (float)(res - 1);
    const float fx = px * rf, fy = py * rf, fz = pz * rf;
    int ix = (int)floorf(fx), iy = (int)floorf(fy), iz = (int)floorf(fz);
    ix = min(max(ix, 0), res - 2);
    iy = min(max(iy, 0), res - 2);
    iz = min(max(iz, 0), res - 2);
    const float tx = fx - (float)ix, ty = fy - (float)iy, tz = fz - (float)iz;
    const float sx = 1.f - tx, sy = 1.f - ty, sz = 1.f - tz;
    float a0 = 0.f, a1 = 0.f;

    if (dense) {
        const int b0 = ix + res * (iy + res * iz);
        v4fu P[4];
        #pragma unroll
        for (int c = 0; c < 4; ++c) {
            const int dy = c >> 1, dz = c & 1;
            P[c] = *(const v4fu*)((const float*)tbl + 2 * (b0 + res * dy + res * res * dz));
        }
        #pragma unroll
        for (int c = 0; c < 4; ++c) {
            const int dy = c >> 1, dz = c & 1;
            const float wyz = (dy ? ty : sy) * (dz ? tz : sz);
            const float w0 = sx * wyz, w1 = tx * wyz;
            a0 = fmaf(w0, P[c].x, a0); a1 = fmaf(w0, P[c].y, a1);
            a0 = fmaf(w1, P[c].z, a0); a1 = fmaf(w1, P[c].w, a1);
        }
    } else {
        uint32_t i0[4], i1[4];
        v4f P[4];
        #pragma unroll
        for (int c = 0; c < 4; ++c) {
            const int dy = c >> 1, dz = c & 1;
            const uint32_t r = (uint32_t)(iy + dy) * PR2 ^ (uint32_t)(iz + dz) * PR3;
            i0[c] = ((uint32_t)ix ^ r) & HMASK;
            i1[c] = ((uint32_t)(ix + 1) ^ r) & HMASK;
            P[c] = *(const v4f*)((const float*)tbl + 2 * (i0[c] & ~1u));
        }
        const bool odd = (ix & 1);
        v2f O[4];
        if (odd) {
            #pragma unroll
            for (int c = 0; c < 4; ++c) O[c] = tbl[i1[c]];
        } else {
            #pragma unroll
            for (int c = 0; c < 4; ++c) { v2f z = {0.f, 0.f}; O[c] = z; }
        }
        #pragma unroll
        for (int c = 0; c < 4; ++c) {
            const int dy = c >> 1, dz = c & 1;
            const bool hi = (i0[c] & 1);
            v2f c0, e;
            c0.x = hi ? P[c].z : P[c].x;  c0.y = hi ? P[c].w : P[c].y;
            e.x  = hi ? P[c].x : P[c].z;  e.y  = hi ? P[c].y : P[c].w;
            const v2f c1 = odd ? O[c] : e;
            const float wyz = (dy ? ty : sy) * (dz ? tz : sz);
            const float w0 = sx * wyz, w1 = tx * wyz;
            a0 = fmaf(w0, c0.x, a0); a1 = fmaf(w0, c0.y, a1);
            a0 = fmaf(w1, c1.x, a0); a1 = fmaf(w1, c1.y, a1);
        }
    }
    A0 = a0; A1 = a1;
}

template<int NLEV>
__global__ __launch_bounds__(256, 8)
void encode_k(const float* __restrict__ x, const float* __restrict__ table,
              u32x2* __restrict__ featT, int n, int lb, ResArr rv)
{
    const int nth2 = gridDim.x * 512;
    for (int q = (blockIdx.x * 256 + threadIdx.x) * 2; q < n; q += nth2) {
        float p0x, p0y, p0z, p1x, p1y, p1z;
        const bool two = (q + 1 < n);
        if (two) {
            const v4fu a = __builtin_nontemporal_load((const v4fu*)(x + 3 * q));
            const v2f  b = __builtin_nontemporal_load((const v2fu*)(x + 3 * q + 4));
            p0x = a.x; p0y = a.y; p0z = a.z; p1x = a.w; p1y = b.x; p1z = b.y;
        } else {
            p0x = x[3 * q]; p0y = x[3 * q + 1]; p0z = x[3 * q + 2];
            p1x = p0x; p1y = p0y; p1z = p0z;
        }
        #pragma unroll
        for (int il = 0; il < NLEV; ++il) {
            const int l = lb + il;
            const int res = rv.r[l];
            const bool dense = ((long long)res * res * res <= (long long)HASH_SZ);
            const v2f* tbl = (const v2f*)table + (size_t)l * HASH_SZ;
            float a00, a01, a10, a11;
            gather_one(tbl, res, dense, p0x, p0y, p0z, a00, a01);
            gather_one(tbl, res, dense, p1x, p1y, p1z, a10, a11);
            if (two) {
                const u32x2 e0 = pack_split2(a00, a01);
                const u32x2 e1 = pack_split2(a10, a11);
                u32x4 st; st.x = e0.x; st.y = e0.y; st.z = e1.x; st.w = e1.y;
                __builtin_nontemporal_store(st, (u32x4*)&featT[(size_t)l * n + q]);
            } else {
                __builtin_nontemporal_store(pack_split2(a00, a01),
                                            &featT[(size_t)l * n + q]);
            }
        }
    }
}

// ---------------- weight prep (layout doubles as A-operand frags) ----------------
__global__ void prep_weights(const float* __restrict__ W1,
                             const float* __restrict__ W2,
                             const float* __restrict__ W3,
                             unsigned short* __restrict__ wb)
{
    const int tid = threadIdx.x;
    const int nb = tid >> 6, lane = tid & 63;
    const int l15 = lane & 15, q = lane >> 4;
    #pragma unroll
    for (int j = 0; j < 8; ++j) {
        const float v = W1[(q * 8 + j) * 64 + nb * 16 + l15];
        const unsigned short h = bf16_rne(v);
        wb[(nb * 64 + lane) * 8 + j] = h;
        wb[2048 + (nb * 64 + lane) * 8 + j] = bf16_rne(v - bf16f(h));
    }
    #pragma unroll
    for (int kb = 0; kb < 2; ++kb) {
        #pragma unroll
        for (int j = 0; j < 8; ++j) {
            const int row = kb * 32 + q * 8 + j;
            const int idx = ((kb * 4 + nb) * 64 + lane) * 8 + j;
            float v = W2[row * 64 + nb * 16 + l15];
            unsigned short h = bf16_rne(v);
            wb[4096 + idx] = h;
            wb[8192 + idx] = bf16_rne(v - bf16f(h));
            v = W3[row * 64 + nb * 16 + l15];
            h = bf16_rne(v);
            wb[12288 + idx] = h;
            wb[16384 + idx] = bf16_rne(v - bf16f(h));
        }
    }
}

// ---------------- MFMA MLP: weights=A, acts=B, no LDS, permlane exchange ----------------
__global__ __launch_bounds__(256, 4)
void mlp_mfma(const u32x2* __restrict__ featT,
              const unsigned short* __restrict__ wb,
              const float* __restrict__ b1, const float* __restrict__ b2,
              const float* __restrict__ b3,
              const float* __restrict__ Wo, const float* __restrict__ bo,
              float* __restrict__ out, int n)
{
    const int wave = threadIdx.x >> 6;
    const int lane = threadIdx.x & 63;
    const int l15 = lane & 15, quad = lane >> 4;
    const int p0 = (blockIdx.x * 4 + wave) * 32;
    if (p0 >= n) return;

    // ---- layer 1: B-frags straight from pre-split featT ----
    bf16x8 bh[2], bl[2];
    #pragma unroll
    for (int t = 0; t < 2; ++t) {
        const int p = p0 + t * 16 + l15;
        const int pl = (p < n) ? p : (n - 1);
        u32x4 hw, lw;
        #pragma unroll
        for (int jj = 0; jj < 4; ++jj) {
            const u32x2 v = featT[(size_t)(quad * 4 + jj) * n + pl];
            hw[jj] = v.x; lw[jj] = v.y;
        }
        bh[t] = *(bf16x8*)&hw;
        bl[t] = *(bf16x8*)&lw;
    }

    f32x4 acc[2][4];
    #pragma unroll
    for (int nb = 0; nb < 4; ++nb) {
        const bf16x8 wh = *(const bf16x8*)(wb + (nb * 64 + lane) * 8);
        const bf16x8 wl = *(const bf16x8*)(wb + 2048 + (nb * 64 + lane) * 8);
        const f32x4 bv = *(const f32x4*)(b1 + nb * 16 + quad * 4);
        #pragma unroll
        for (int t = 0; t < 2; ++t) {
            f32x4 c = bv;
            c = __builtin_amdgcn_mfma_f32_16x16x32_bf16(wh, bl[t], c, 0, 0, 0);
            c = __builtin_amdgcn_mfma_f32_16x16x32_bf16(wl, bh[t], c, 0, 0, 0);
            c = __builtin_amdgcn_mfma_f32_16x16x32_bf16(wh, bh[t], c, 0, 0, 0);
            acc[t][nb] = c;
        }
    }

    // ---- hidden layers 2 & 3 ----
    #pragma unroll
    for (int layer = 0; layer < 2; ++layer) {
        // C-layout -> B-frag layout, pure VALU.
        // x = relu(acc[2kb]) (neurons kb*32+0..15), y = relu(acc[2kb+1]) (+16).
        // swap32(dst=x,src=y): x={xq0,xq1|yq0,yq1}, y={xq2,xq3|yq2,yq3}
        // swap16(dst=x,src=y): x={xq0,xq2,yq0,yq2}=v[r], y={xq1,xq3,yq1,yq3}=v[4+r]
        bf16x8 nh[2][2], nl[2][2];
        #pragma unroll
        for (int t = 0; t < 2; ++t) {
            #pragma unroll
            for (int kb = 0; kb < 2; ++kb) {
                float v[8];
                #pragma unroll
                for (int rr = 0; rr < 4; ++rr) {
                    float xq = fmaxf(acc[t][2 * kb][rr],     0.f);
                    float yq = fmaxf(acc[t][2 * kb + 1][rr], 0.f);
                    asm("v_permlane32_swap_b32 %0, %1" : "+v"(xq), "+v"(yq));
                    asm("v_permlane16_swap_b32 %0, %1" : "+v"(xq), "+v"(yq));
                    v[rr]     = xq;   // k = quad*8 + rr
                    v[4 + rr] = yq;   // k = quad*8 + 4 + rr
                }
                split8(v, nh[t][kb], nl[t][kb]);
            }
        }
        const int base_h = layer ? 12288 : 4096;
        const int base_l = layer ? 16384 : 8192;
        const float* __restrict__ bias = layer ? b3 : b2;
        #pragma unroll
        for (int nb = 0; nb < 4; ++nb) {
            const f32x4 bv = *(const f32x4*)(bias + nb * 16 + quad * 4);
            f32x4 c[2];
            #pragma unroll
            for (int t = 0; t < 2; ++t) c[t] = bv;
            #pragma unroll
            for (int kb = 0; kb < 2; ++kb) {
                const int idx = ((kb * 4 + nb) * 64 + lane) * 8;
                const bf16x8 wh = *(const bf16x8*)(wb + base_h + idx);
                const bf16x8 wl = *(const bf16x8*)(wb + base_l + idx);
                #pragma unroll
                for (int t = 0; t < 2; ++t) {
                    c[t] = __builtin_amdgcn_mfma_f32_16x16x32_bf16(wh, nl[t][kb], c[t], 0, 0, 0);
                    c[t] = __builtin_amdgcn_mfma_f32_16x16x32_bf16(wl, nh[t][kb], c[t], 0, 0, 0);
                    c[t] = __builtin_amdgcn_mfma_f32_16x16x32_bf16(wh, nh[t][kb], c[t], 0, 0, 0);
                }
            }
            #pragma unroll
            for (int t = 0; t < 2; ++t) acc[t][nb] = c[t];
        }
    }

    // ---- output layer: lane holds 16 neurons of point l15; quad-reduce ----
    float part[2];
    #pragma unroll
    for (int t = 0; t < 2; ++t) {
        float s = 0.f;
        #pragma unroll
        for (int nb = 0; nb < 4; ++nb) {
            const f32x4 wo4 = *(const f32x4*)(Wo + nb * 16 + quad * 4);
            #pragma unroll
            for (int r = 0; r < 4; ++r)
                s = fmaf(fmaxf(acc[t][nb][r], 0.f), wo4[r], s);
        }
        part[t] = s;
    }
    #pragma unroll
    for (int t = 0; t < 2; ++t) {
        part[t] += __shfl_xor(part[t], 16, 64);
        part[t] += __shfl_xor(part[t], 32, 64);
    }
    if (quad == 0) {
        const float b = bo[0];
        #pragma unroll
        for (int t = 0; t < 2; ++t) {
            const int po = p0 + t * 16 + l15;
            if (po < n) out[po] = part[t] + b;
        }
    }
}

// ---------------- fp32 MLP (ws-fallback path) ----------------
__global__ __launch_bounds__(256, 3)
void mlp_forward(const u32x2* __restrict__ featT,
                 const float* __restrict__ W1, const float* __restrict__ b1,
                 const float* __restrict__ W2, const float* __restrict__ b2,
                 const float* __restrict__ W3, const float* __restrict__ b3,
                 const float* __restrict__ Wo, const float* __restrict__ bo,
                 float* __restrict__ out, int n)
{
    const int p = blockIdx.x * 256 + threadIdx.x;
    if (p >= n) return;
    const v2f z2 = {0.f, 0.f};
    v2f A[32], B[32];
    #pragma unroll
    for (int jq = 0; jq < 16; ++jq) {
        const v4f b = *(const v4f*)(b1 + 4 * jq);
        A[2 * jq] = b.xy; A[2 * jq + 1] = b.zw;
    }
    #pragma unroll
    for (int l = 0; l < 16; ++l) {
        const u32x2 e = __builtin_nontemporal_load(&featT[(size_t)l * n + p]);
        union { u32 u; float f; } h0, h1, l0, l1;
        h0.u = e.x << 16; h1.u = e.x & 0xffff0000u;
        l0.u = e.y << 16; l1.u = e.y & 0xffff0000u;
        v2f f; f.x = h0.f + l0.f; f.y = h1.f + l1.f;
        const v4f* w0 = (const v4f*)(W1 + (size_t)(2 * l) * 64);
        const v4f* w1 = (const v4f*)(W1 + (size_t)(2 * l + 1) * 64);
        const v2f hh0 = {f.x, f.x}, hh1 = {f.y, f.y};
        #pragma unroll
        for (int jq = 0; jq < 16; ++jq) {
            const v4f wa = w0[jq];
            A[2 * jq]     = __builtin_elementwise_fma(hh0, wa.xy, A[2 * jq]);
            A[2 * jq + 1] = __builtin_elementwise_fma(hh0, wa.zw, A[2 * jq + 1]);
        }
        #pragma unroll
        for (int jq = 0; jq < 16; ++jq) {
            const v4f wb2 = w1[jq];
            A[2 * jq]     = __builtin_elementwise_fma(hh1, wb2.xy, A[2 * jq]);
            A[2 * jq + 1] = __builtin_elementwise_fma(hh1, wb2.zw, A[2 * jq + 1]);
        }
    }
    #pragma unroll
    for (int j = 0; j < 32; ++j) A[j] = __builtin_elementwise_max(A[j], z2);
    #pragma unroll
    for (int jq = 0; jq < 16; ++jq) {
        const v4f b = *(const v4f*)(b2 + 4 * jq);
        B[2 * jq] = b.xy; B[2 * jq + 1] = b.zw;
    }
    #pragma unroll
    for (int k = 0; k < 64; ++k) {
        const float hv = A[k >> 1][k & 1];
        const v2f h = {hv, hv};
        const v4f* w = (const v4f*)(W2 + (size_t)k * 64);
        #pragma unroll
        for (int jq = 0; jq < 16; ++jq) {
            const v4f wa = w[jq];
            B[2 * jq]     = __builtin_elementwise_fma(h, wa.xy, B[2 * jq]);
            B[2 * jq + 1] = __builtin_elementwise_fma(h, wa.zw, B[2 * jq + 1]);
        }
    }
    #pragma unroll
    for (int j = 0; j < 32; ++j) B[j] = __builtin_elementwise_max(B[j], z2);
    #pragma unroll
    for (int jq = 0; jq < 16; ++jq) {
        const v4f b = *(const v4f*)(b3 + 4 * jq);
        A[2 * jq] = b.xy; A[2 * jq + 1] = b.zw;
    }
    #pragma unroll
    for (int k = 0; k < 64; ++k) {
        const float hv = B[k >> 1][k & 1];
        const v2f h = {hv, hv};
        const v4f* w = (const v4f*)(W3 + (size_t)k * 64);
        #pragma unroll
        for (int jq = 0; jq < 16; ++jq) {
            const v4f wa = w[jq];
            A[2 * jq]     = __builtin_elementwise_fma(h, wa.xy, A[2 * jq]);
            A[2 * jq + 1] = __builtin_elementwise_fma(h, wa.zw, A[2 * jq + 1]);
        }
    }
    v2f o2 = z2;
    #pragma unroll
    for (int jq = 0; jq < 16; ++jq) {
        const v4f wa = *(const v4f*)(Wo + 4 * jq);
        o2 = __builtin_elementwise_fma(__builtin_elementwise_max(A[2 * jq], z2),     wa.xy, o2);
        o2 = __builtin_elementwise_fma(__builtin_elementwise_max(A[2 * jq + 1], z2), wa.zw, o2);
    }
    out[p] = o2.x + o2.y + bo[0];
}

// ---------------- fallback (ws too small): R1-style fused ----------------
__global__ __launch_bounds__(256, 2)
void hashpinn_fused(const float* __restrict__ x,
                    const float* __restrict__ table,
                    const float* __restrict__ W1, const float* __restrict__ b1,
                    const float* __restrict__ W2, const float* __restrict__ b2,
                    const float* __restrict__ W3, const float* __restrict__ b3,
                    const float* __restrict__ Wo, const float* __restrict__ bo,
                    float* __restrict__ out, int n, ResArr rv)
{
    const int p = blockIdx.x * 256 + threadIdx.x;
    if (p >= n) return;
    const float px = x[3*p+0], py = x[3*p+1], pz = x[3*p+2];
    float feat[32];
    #pragma unroll
    for (int l = 0; l < 16; ++l) {
        const int res = rv.r[l];
        const float rf = (float)(res - 1);
        const float fx = px*rf, fy = py*rf, fz = pz*rf;
        int ix=(int)floorf(fx), iy=(int)floorf(fy), iz=(int)floorf(fz);
        ix=min(max(ix,0),res-2); iy=min(max(iy,0),res-2); iz=min(max(iz,0),res-2);
        const float tx=fx-(float)ix, ty=fy-(float)iy, tz=fz-(float)iz;
        const float sx=1.f-tx, sy=1.f-ty, sz=1.f-tz;
        const float2* tbl=(const float2*)table+(size_t)l*HASH_SZ;
        const bool dense=((long long)res*res*res<=(long long)HASH_SZ);
        float a0=0.f, a1=0.f;
        #pragma unroll
        for (int c=0;c<8;++c){
            const uint32_t cx=(uint32_t)(ix+((c>>2)&1));
            const uint32_t cy=(uint32_t)(iy+((c>>1)&1));
            const uint32_t cz=(uint32_t)(iz+(c&1));
            uint32_t idx = dense ? cx+(uint32_t)res*(cy+(uint32_t)res*cz)
                                 : ((cx*1u ^ cy*PR2 ^ cz*PR3)&HMASK);
            const float2 v=tbl[idx];
            const float w=(((c>>2)&1)?tx:sx)*(((c>>1)&1)?ty:sy)*((c&1)?tz:sz);
            a0=fmaf(w,v.x,a0); a1=fmaf(w,v.y,a1);
        }
        feat[2*l]=a0; feat[2*l+1]=a1;
    }
    float A[64], B[64];
    #pragma unroll
    for (int j=0;j<64;++j) A[j]=b1[j];
    #pragma unroll
    for (int k=0;k<32;++k){ const float h=feat[k];
        #pragma unroll
        for (int j=0;j<64;++j) A[j]=fmaf(h,W1[k*64+j],A[j]); }
    #pragma unroll 1
    for (int it=0;it<2;++it){
        const float* W = it?W3:W2; const float* bb = it?b3:b2;
        #pragma unroll
        for (int j=0;j<64;++j){ A[j]=fmaxf(A[j],0.f); B[j]=bb[j]; }
        #pragma unroll
        for (int k=0;k<64;++k){ const float h=A[k];
            #pragma unroll
            for (int j=0;j<64;++j) B[j]=fmaf(h,W[k*64+j],B[j]); }
        #pragma unroll
        for (int j=0;j<64;++j) A[j]=B[j];
    }
    float o=bo[0];
    #pragma unroll
    for (int j=0;j<64;++j) o=fmaf(fmaxf(A[j],0.f),Wo[j],o);
    out[p]=o;
}

static inline void launch_encode(int nlev, const float* x, const float* table,
                                 u32x2* featT, int n, int lb, const ResArr& rv,
                                 hipStream_t stream) {
    const dim3 g(4096), b(256);
    switch (nlev) {
        case 1: hipLaunchKernelGGL(encode_k<1>, g, b, 0, stream, x, table, featT, n, lb, rv); break;
        case 2: hipLaunchKernelGGL(encode_k<2>, g, b, 0, stream, x, table, featT, n, lb, rv); break;
        case 3: hipLaunchKernelGGL(encode_k<3>, g, b, 0, stream, x, table, featT, n, lb, rv); break;
        case 4: hipLaunchKernelGGL(encode_k<4>, g, b, 0, stream, x, table, featT, n, lb, rv); break;
        case 5: hipLaunchKernelGGL(encode_k<5>, g, b, 0, stream, x, table, featT, n, lb, rv); break;
        case 6: hipLaunchKernelGGL(encode_k<6>, g, b, 0, stream, x, table, featT, n, lb, rv); break;
        case 7: hipLaunchKernelGGL(encode_k<7>, g, b, 0, stream, x, table, featT, n, lb, rv); break;
        default: hipLaunchKernelGGL(encode_k<8>, g, b, 0, stream, x, table, featT, n, lb, rv); break;
    }
}

extern "C" void kernel_launch(void* const* d_in, const int* in_sizes, int n_in,
                              void* d_out, int out_size, void* d_ws, size_t ws_size,
                              hipStream_t stream) {
    const float* x     = (const float*)d_in[0];
    const float* table = (const float*)d_in[1];
    const float* W1    = (const float*)d_in[2];
    const float* b1    = (const float*)d_in[3];
    const float* W2    = (const float*)d_in[4];
    const float* b2    = (const float*)d_in[5];
    const float* W3    = (const float*)d_in[6];
    const float* b3    = (const float*)d_in[7];
    const float* Wo    = (const float*)d_in[8];
    const float* bo    = (const float*)d_in[9];
    float* out = (float*)d_out;

    const int n = in_sizes[0] / 3;

    ResArr rv;
    const double scale = std::exp2(std::log2(2048.0 / 16.0) / 15.0);
    for (int l = 0; l < 16; ++l)
        rv.r[l] = (int)std::ceil(16.0 * std::pow(scale, (double)l));

    int dense_end = 0;
    while (dense_end < 16) {
        long long r = rv.r[dense_end];
        if (r * r * r <= (long long)HASH_SZ) ++dense_end; else break;
    }
    if (dense_end > 8) dense_end = 8;

    const size_t feat_bytes = (size_t)n * 16 * sizeof(u32x2);
    const size_t wb_bytes = 20480 * sizeof(unsigned short);

    if (ws_size >= feat_bytes + wb_bytes) {
        u32x2* featT = (u32x2*)d_ws;
        unsigned short* wb = (unsigned short*)((char*)d_ws + feat_bytes);

        hipLaunchKernelGGL(prep_weights, dim3(1), dim3(256), 0, stream, W1, W2, W3, wb);

        if (dense_end > 0)
            launch_encode(dense_end, x, table, featT, n, 0, rv, stream);
        for (int l = dense_end; l < 16; ++l)
            launch_encode(1, x, table, featT, n, l, rv, stream);

        const int nblocks = (n + 127) / 128;   // 128 pts/block (4 waves x 32)
        hipLaunchKernelGGL(mlp_mfma, dim3(nblocks), dim3(256), 0, stream,
                           featT, wb, b1, b2, b3, Wo, bo, out, n);
    } else if (ws_size >= feat_bytes) {
        u32x2* featT = (u32x2*)d_ws;
        if (dense_end > 0)
            launch_encode(dense_end, x, table, featT, n, 0, rv, stream);
        for (int l = dense_end; l < 16; ++l)
            launch_encode(1, x, table, featT, n, l, rv, stream);
        hipLaunchKernelGGL(mlp_forward, dim3((n + 255) / 256), dim3(256), 0, stream,
                           featT, W1, b1, W2, b2, W3, b3, Wo, bo, out, n);
    } else {
        hipLaunchKernelGGL(hashpinn_fused, dim3((n + 255) / 256), dim3(256), 0, stream,
                           x, table, W1, b1, W2, b2, W3, b3, Wo, bo, out, n, rv);
    }
}

// Round 4
// 1076.874 us; speedup vs baseline: 1.0519x; 1.0005x over previous
//
#include <hip/hip_runtime.h>
#include <hip/hip_fp16.h>
#include <cmath>
#include <cstdint>

// HashPINN R13:
//  - Encode is the dominant cost (~880 of 1077 us) and is MSHR-bound:
//    ~47K random line-misses/CU/level at ~250cy L2 latency = ~65 outstanding
//    = the per-CU miss-queue wall. Levers: fewer requests, lower latency.
//  - Tables converted once per launch to fp16 pairs (4B/entry, abs err
//    <= 2^-25 ~ 3e-8; output delta ~5e-8 vs 1.1e-6 threshold):
//      * hashed: 16B window = 4 entries; (ix^r, (ix+1)^r) share the window
//        iff ix&3 != 3 -> extra-load probability 1/2 -> 1/4; 6 -> 5
//        requests/point (-17%).
//      * dense: &~1u window always covers the adjacent pair (same 4 loads,
//        half bytes); coarse tables now L1-friendlier.
//      * table/level 4MB -> 2MB: half the per-XCD L2 -> better residency
//        alongside x/featT streams.
//  - Extraction via scalar ternaries (cndmask) only - no runtime vector
//    indexing (avoids scratch).  cvt_table: ~15us/launch (64MB->32MB).
//  - mlp_mfma / prep_weights unchanged from R12 (183us; permlane exchange,
//    no LDS, no spills). fp32 encode kept as ws-fallback.

#define HASH_SZ (1u << 19)
#define HMASK   (HASH_SZ - 1u)
#define PR2 2654435761u
#define PR3 805459861u

typedef float v2f __attribute__((ext_vector_type(2)));
typedef float v4f __attribute__((ext_vector_type(4)));
typedef v4f v4fu __attribute__((aligned(8)));
typedef v2f v2fu __attribute__((aligned(8)));
typedef short bf16x8 __attribute__((ext_vector_type(8)));
typedef float f32x4 __attribute__((ext_vector_type(4)));
typedef unsigned int u32;
typedef u32 u32x2 __attribute__((ext_vector_type(2)));
typedef u32 u32x4 __attribute__((ext_vector_type(4)));
typedef u32x4 u32x4u __attribute__((aligned(8)));

struct ResArr { int r[16]; };

// ---------- bf16 helpers ----------
__device__ __forceinline__ unsigned short bf16_rne(float f) {
    union { float f; unsigned u; } v; v.f = f;
    unsigned u = v.u;
    unsigned r = (u + 0x7fffu + ((u >> 16) & 1u)) >> 16;
    return (unsigned short)r;
}
__device__ __forceinline__ float bf16f(unsigned short h) {
    union { unsigned u; float f; } v; v.u = ((unsigned)h) << 16;
    return v.f;
}
// hi = TRUNCATED bf16 (cheap); lo = RNE bf16 of the exact remainder.
__device__ __forceinline__ void split8(const float* x, bf16x8& hi, bf16x8& lo) {
    #pragma unroll
    for (int j = 0; j < 8; ++j) {
        union { float f; unsigned u; } v; v.f = x[j];
        const unsigned hu = v.u & 0xffff0000u;
        hi[j] = (short)(hu >> 16);
        union { unsigned u; float f; } hf; hf.u = hu;
        const float d = x[j] - hf.f;
        union { float f; unsigned u; } dv; dv.f = d;
        lo[j] = (short)((dv.u + 0x7fffu + ((dv.u >> 16) & 1u)) >> 16);
    }
}
__device__ __forceinline__ u32 rne16u(float f) {
    union { float f; u32 u; } v; v.f = f;
    return (v.u + 0x7fffu + ((v.u >> 16) & 1u)) >> 16;
}
// pack two features into {hi0|hi1<<16, lo0|lo1<<16} (bit-identical to split8)
__device__ __forceinline__ u32x2 pack_split2(float f0, float f1) {
    union { float f; u32 u; } a, b; a.f = f0; b.f = f1;
    const u32 h0 = a.u & 0xffff0000u, h1 = b.u & 0xffff0000u;
    union { u32 u; float f; } ha, hb; ha.u = h0; hb.u = h1;
    u32x2 r;
    r.x = (h0 >> 16) | h1;
    r.y = rne16u(f0 - ha.f) | (rne16u(f1 - hb.f) << 16);
    return r;
}

// ---------- fp16 helpers ----------
__device__ __forceinline__ u32 pkh(float f0, float f1) {
    const __half h0 = __float2half_rn(f0), h1 = __float2half_rn(f1);
    return (u32)__half_as_ushort(h0) | ((u32)__half_as_ushort(h1) << 16);
}
__device__ __forceinline__ v2f cvt2(u32 e) {
    __half2 h;
    *reinterpret_cast<u32*>(&h) = e;
    v2f r; r.x = __low2float(h); r.y = __high2float(h);
    return r;
}
// select entry k (0..3) from a 16B window without runtime vector indexing
__device__ __forceinline__ u32 sel4(u32x4 P, u32 k) {
    const u32 a = (k & 1u) ? P.y : P.x;
    const u32 b = (k & 1u) ? P.w : P.z;
    return (k & 2u) ? b : a;
}

// ---------------- table conversion: fp32 pairs -> packed fp16 ----------------
__global__ __launch_bounds__(256, 8)
void cvt_table(const float* __restrict__ table, u32* __restrict__ tab16, int total)
{
    const int e0 = (blockIdx.x * 256 + threadIdx.x) * 4;
    if (e0 >= total) return;
    const v4f a = __builtin_nontemporal_load((const v4f*)(table + 2 * (size_t)e0));
    const v4f b = __builtin_nontemporal_load((const v4f*)(table + 2 * (size_t)e0 + 4));
    u32x4 o;
    o.x = pkh(a.x, a.y); o.y = pkh(a.z, a.w);
    o.z = pkh(b.x, b.y); o.w = pkh(b.z, b.w);
    *(u32x4*)(tab16 + e0) = o;
}

// ---------------- fp16-table gather ----------------
__device__ __forceinline__ void gather16_one(
    const u32* __restrict__ tab, int res, bool dense,
    float px, float py, float pz, float& A0, float& A1)
{
    const float rf = (float)(res - 1);
    const float fx = px * rf, fy = py * rf, fz = pz * rf;
    int ix = (int)floorf(fx), iy = (int)floorf(fy), iz = (int)floorf(fz);
    ix = min(max(ix, 0), res - 2);
    iy = min(max(iy, 0), res - 2);
    iz = min(max(iz, 0), res - 2);
    const float tx = fx - (float)ix, ty = fy - (float)iy, tz = fz - (float)iz;
    const float sx = 1.f - tx, sy = 1.f - ty, sz = 1.f - tz;
    float a0 = 0.f, a1 = 0.f;

    if (dense) {
        const int b0 = ix + res * (iy + res * iz);
        #pragma unroll
        for (int c = 0; c < 4; ++c) {
            const int dy = c >> 1, dz = c & 1;
            const u32 idx0 = (u32)(b0 + res * dy + res * res * dz);
            const u32x4u Pv = *(const u32x4u*)(tab + (idx0 & ~1u));
            const bool hi = (idx0 & 1u) != 0u;
            const u32 e0 = hi ? Pv.y : Pv.x;
            const u32 e1 = hi ? Pv.z : Pv.y;
            const float wyz = (dy ? ty : sy) * (dz ? tz : sz);
            const float w0 = sx * wyz, w1 = tx * wyz;
            const v2f f0 = cvt2(e0), f1 = cvt2(e1);
            a0 = fmaf(w0, f0.x, a0); a1 = fmaf(w0, f0.y, a1);
            a0 = fmaf(w1, f1.x, a0); a1 = fmaf(w1, f1.y, a1);
        }
    } else {
        u32 i1a[4], k0[4];
        u32x4 P[4];
        #pragma unroll
        for (int c = 0; c < 4; ++c) {
            const int dy = c >> 1, dz = c & 1;
            const u32 r = (u32)(iy + dy) * PR2 ^ (u32)(iz + dz) * PR3;
            const u32 i0 = ((u32)ix ^ r) & HMASK;
            i1a[c] = ((u32)(ix + 1) ^ r) & HMASK;
            k0[c] = i0 & 3u;
            P[c] = *(const u32x4*)(tab + (i0 & ~3u));
        }
        const bool extra = ((ix & 3) == 3);   // (ix^(ix+1)) spans the 4-window
        u32 O[4];
        if (extra) {
            #pragma unroll
            for (int c = 0; c < 4; ++c) O[c] = tab[i1a[c]];
        } else {
            #pragma unroll
            for (int c = 0; c < 4; ++c) O[c] = 0u;
        }
        #pragma unroll
        for (int c = 0; c < 4; ++c) {
            const int dy = c >> 1, dz = c & 1;
            const u32 e0 = sel4(P[c], k0[c]);
            const u32 e1w = sel4(P[c], i1a[c] & 3u);
            const u32 e1 = extra ? O[c] : e1w;
            const float wyz = (dy ? ty : sy) * (dz ? tz : sz);
            const float w0 = sx * wyz, w1 = tx * wyz;
            const v2f f0 = cvt2(e0), f1 = cvt2(e1);
            a0 = fmaf(w0, f0.x, a0); a1 = fmaf(w0, f0.y, a1);
            a0 = fmaf(w1, f1.x, a0); a1 = fmaf(w1, f1.y, a1);
        }
    }
    A0 = a0; A1 = a1;
}

template<int NLEV>
__global__ __launch_bounds__(256, 8)
void encode16_k(const float* __restrict__ x, const u32* __restrict__ tab16,
                u32x2* __restrict__ featT, int n, int lb, ResArr rv)
{
    const int nth2 = gridDim.x * 512;
    for (int q = (blockIdx.x * 256 + threadIdx.x) * 2; q < n; q += nth2) {
        float p0x, p0y, p0z, p1x, p1y, p1z;
        const bool two = (q + 1 < n);
        if (two) {
            const v4fu a = __builtin_nontemporal_load((const v4fu*)(x + 3 * q));
            const v2f  b = __builtin_nontemporal_load((const v2fu*)(x + 3 * q + 4));
            p0x = a.x; p0y = a.y; p0z = a.z; p1x = a.w; p1y = b.x; p1z = b.y;
        } else {
            p0x = x[3 * q]; p0y = x[3 * q + 1]; p0z = x[3 * q + 2];
            p1x = p0x; p1y = p0y; p1z = p0z;
        }
        #pragma unroll
        for (int il = 0; il < NLEV; ++il) {
            const int l = lb + il;
            const int res = rv.r[l];
            const bool dense = ((long long)res * res * res <= (long long)HASH_SZ);
            const u32* tbl = tab16 + (size_t)l * HASH_SZ;
            float a00, a01, a10, a11;
            gather16_one(tbl, res, dense, p0x, p0y, p0z, a00, a01);
            gather16_one(tbl, res, dense, p1x, p1y, p1z, a10, a11);
            if (two) {
                const u32x2 e0 = pack_split2(a00, a01);
                const u32x2 e1 = pack_split2(a10, a11);
                u32x4 st; st.x = e0.x; st.y = e0.y; st.z = e1.x; st.w = e1.y;
                __builtin_nontemporal_store(st, (u32x4*)&featT[(size_t)l * n + q]);
            } else {
                __builtin_nontemporal_store(pack_split2(a00, a01),
                                            &featT[(size_t)l * n + q]);
            }
        }
    }
}

// ---------------- fp32 encode (ws-fallback path, unchanged R12) ----------------
__device__ __forceinline__ void gather_one(
    const v2f* __restrict__ tbl, int res, bool dense,
    float px, float py, float pz, float& A0, float& A1)
{
    const float rf = (float)(res - 1);
    const float fx = px * rf, fy = py * rf, fz = pz * rf;
    int ix = (int)floorf(fx), iy = (int)floorf(fy), iz = (int)floorf(fz);
    ix = min(max(ix, 0), res - 2);
    iy = min(max(iy, 0), res - 2);
    iz = min(max(iz, 0), res - 2);
    const float tx = fx - (float)ix, ty = fy - (float)iy, tz = fz - (float)iz;
    const float sx = 1.f - tx, sy = 1.f - ty, sz = 1.f - tz;
    float a0 = 0.f, a1 = 0.f;

    if (dense) {
        const int b0 = ix + res * (iy + res * iz);
        v4fu P[4];
        #pragma unroll
        for (int c = 0; c < 4; ++c) {
            const int dy = c >> 1, dz = c & 1;
            P[c] = *(const v4fu*)((const float*)tbl + 2 * (b0 + res * dy + res * res * dz));
        }
        #pragma unroll
        for (int c = 0; c < 4; ++c) {
            const int dy = c >> 1, dz = c & 1;
            const float wyz = (dy ? ty : sy) * (dz ? tz : sz);
            const float w0 = sx * wyz, w1 = tx * wyz;
            a0 = fmaf(w0, P[c].x, a0); a1 = fmaf(w0, P[c].y, a1);
            a0 = fmaf(w1, P[c].z, a0); a1 = fmaf(w1, P[c].w, a1);
        }
    } else {
        uint32_t i0[4], i1[4];
        v4f P[4];
        #pragma unroll
        for (int c = 0; c < 4; ++c) {
            const int dy = c >> 1, dz = c & 1;
            const uint32_t r = (uint32_t)(iy + dy) * PR2 ^ (uint32_t)(iz + dz) * PR3;
            i0[c] = ((uint32_t)ix ^ r) & HMASK;
            i1[c] = ((uint32_t)(ix + 1) ^ r) & HMASK;
            P[c] = *(const v4f*)((const float*)tbl + 2 * (i0[c] & ~1u));
        }
        const bool odd = (ix & 1);
        v2f O[4];
        if (odd) {
            #pragma unroll
            for (int c = 0; c < 4; ++c) O[c] = tbl[i1[c]];
        } else {
            #pragma unroll
            for (int c = 0; c < 4; ++c) { v2f z = {0.f, 0.f}; O[c] = z; }
        }
        #pragma unroll
        for (int c = 0; c < 4; ++c) {
            const int dy = c >> 1, dz = c & 1;
            const bool hi = (i0[c] & 1);
            v2f c0, e;
            c0.x = hi ? P[c].z : P[c].x;  c0.y = hi ? P[c].w : P[c].y;
            e.x  = hi ? P[c].x : P[c].z;  e.y  = hi ? P[c].y : P[c].w;
            const v2f c1 = odd ? O[c] : e;
            const float wyz = (dy ? ty : sy) * (dz ? tz : sz);
            const float w0 = sx * wyz, w1 = tx * wyz;
            a0 = fmaf(w0, c0.x, a0); a1 = fmaf(w0, c0.y, a1);
            a0 = fmaf(w1, c1.x, a0); a1 = fmaf(w1, c1.y, a1);
        }
    }
    A0 = a0; A1 = a1;
}

template<int NLEV>
__global__ __launch_bounds__(256, 8)
void encode_k(const float* __restrict__ x, const float* __restrict__ table,
              u32x2* __restrict__ featT, int n, int lb, ResArr rv)
{
    const int nth2 = gridDim.x * 512;
    for (int q = (blockIdx.x * 256 + threadIdx.x) * 2; q < n; q += nth2) {
        float p0x, p0y, p0z, p1x, p1y, p1z;
        const bool two = (q + 1 < n);
        if (two) {
            const v4fu a = __builtin_nontemporal_load((const v4fu*)(x + 3 * q));
            const v2f  b = __builtin_nontemporal_load((const v2fu*)(x + 3 * q + 4));
            p0x = a.x; p0y = a.y; p0z = a.z; p1x = a.w; p1y = b.x; p1z = b.y;
        } else {
            p0x = x[3 * q]; p0y = x[3 * q + 1]; p0z = x[3 * q + 2];
            p1x = p0x; p1y = p0y; p1z = p0z;
        }
        #pragma unroll
        for (int il = 0; il < NLEV; ++il) {
            const int l = lb + il;
            const int res = rv.r[l];
            const bool dense = ((long long)res * res * res <= (long long)HASH_SZ);
            const v2f* tbl = (const v2f*)table + (size_t)l * HASH_SZ;
            float a00, a01, a10, a11;
            gather_one(tbl, res, dense, p0x, p0y, p0z, a00, a01);
            gather_one(tbl, res, dense, p1x, p1y, p1z, a10, a11);
            if (two) {
                const u32x2 e0 = pack_split2(a00, a01);
                const u32x2 e1 = pack_split2(a10, a11);
                u32x4 st; st.x = e0.x; st.y = e0.y; st.z = e1.x; st.w = e1.y;
                __builtin_nontemporal_store(st, (u32x4*)&featT[(size_t)l * n + q]);
            } else {
                __builtin_nontemporal_store(pack_split2(a00, a01),
                                            &featT[(size_t)l * n + q]);
            }
        }
    }
}

// ---------------- weight prep (layout doubles as A-operand frags) ----------------
__global__ void prep_weights(const float* __restrict__ W1,
                             const float* __restrict__ W2,
                             const float* __restrict__ W3,
                             unsigned short* __restrict__ wb)
{
    const int tid = threadIdx.x;
    const int nb = tid >> 6, lane = tid & 63;
    const int l15 = lane & 15, q = lane >> 4;
    #pragma unroll
    for (int j = 0; j < 8; ++j) {
        const float v = W1[(q * 8 + j) * 64 + nb * 16 + l15];
        const unsigned short h = bf16_rne(v);
        wb[(nb * 64 + lane) * 8 + j] = h;
        wb[2048 + (nb * 64 + lane) * 8 + j] = bf16_rne(v - bf16f(h));
    }
    #pragma unroll
    for (int kb = 0; kb < 2; ++kb) {
        #pragma unroll
        for (int j = 0; j < 8; ++j) {
            const int row = kb * 32 + q * 8 + j;
            const int idx = ((kb * 4 + nb) * 64 + lane) * 8 + j;
            float v = W2[row * 64 + nb * 16 + l15];
            unsigned short h = bf16_rne(v);
            wb[4096 + idx] = h;
            wb[8192 + idx] = bf16_rne(v - bf16f(h));
            v = W3[row * 64 + nb * 16 + l15];
            h = bf16_rne(v);
            wb[12288 + idx] = h;
            wb[16384 + idx] = bf16_rne(v - bf16f(h));
        }
    }
}

// ---------------- MFMA MLP: weights=A, acts=B, no LDS, permlane exchange ----------------
__global__ __launch_bounds__(256, 4)
void mlp_mfma(const u32x2* __restrict__ featT,
              const unsigned short* __restrict__ wb,
              const float* __restrict__ b1, const float* __restrict__ b2,
              const float* __restrict__ b3,
              const float* __restrict__ Wo, const float* __restrict__ bo,
              float* __restrict__ out, int n)
{
    const int wave = threadIdx.x >> 6;
    const int lane = threadIdx.x & 63;
    const int l15 = lane & 15, quad = lane >> 4;
    const int p0 = (blockIdx.x * 4 + wave) * 32;
    if (p0 >= n) return;

    // ---- layer 1: B-frags straight from pre-split featT ----
    bf16x8 bh[2], bl[2];
    #pragma unroll
    for (int t = 0; t < 2; ++t) {
        const int p = p0 + t * 16 + l15;
        const int pl = (p < n) ? p : (n - 1);
        u32x4 hw, lw;
        #pragma unroll
        for (int jj = 0; jj < 4; ++jj) {
            const u32x2 v = featT[(size_t)(quad * 4 + jj) * n + pl];
            hw[jj] = v.x; lw[jj] = v.y;
        }
        bh[t] = *(bf16x8*)&hw;
        bl[t] = *(bf16x8*)&lw;
    }

    f32x4 acc[2][4];
    #pragma unroll
    for (int nb = 0; nb < 4; ++nb) {
        const bf16x8 wh = *(const bf16x8*)(wb + (nb * 64 + lane) * 8);
        const bf16x8 wl = *(const bf16x8*)(wb + 2048 + (nb * 64 + lane) * 8);
        const f32x4 bv = *(const f32x4*)(b1 + nb * 16 + quad * 4);
        #pragma unroll
        for (int t = 0; t < 2; ++t) {
            f32x4 c = bv;
            c = __builtin_amdgcn_mfma_f32_16x16x32_bf16(wh, bl[t], c, 0, 0, 0);
            c = __builtin_amdgcn_mfma_f32_16x16x32_bf16(wl, bh[t], c, 0, 0, 0);
            c = __builtin_amdgcn_mfma_f32_16x16x32_bf16(wh, bh[t], c, 0, 0, 0);
            acc[t][nb] = c;
        }
    }

    // ---- hidden layers 2 & 3 ----
    #pragma unroll
    for (int layer = 0; layer < 2; ++layer) {
        // C-layout -> B-frag layout, pure VALU.
        // swap32(dst=x,src=y): x={xq0,xq1|yq0,yq1}, y={xq2,xq3|yq2,yq3}
        // swap16(dst=x,src=y): x={xq0,xq2,yq0,yq2}=v[r], y={xq1,xq3,yq1,yq3}=v[4+r]
        bf16x8 nh[2][2], nl[2][2];
        #pragma unroll
        for (int t = 0; t < 2; ++t) {
            #pragma unroll
            for (int kb = 0; kb < 2; ++kb) {
                float v[8];
                #pragma unroll
                for (int rr = 0; rr < 4; ++rr) {
                    float xq = fmaxf(acc[t][2 * kb][rr],     0.f);
                    float yq = fmaxf(acc[t][2 * kb + 1][rr], 0.f);
                    asm("v_permlane32_swap_b32 %0, %1" : "+v"(xq), "+v"(yq));
                    asm("v_permlane16_swap_b32 %0, %1" : "+v"(xq), "+v"(yq));
                    v[rr]     = xq;   // k = quad*8 + rr
                    v[4 + rr] = yq;   // k = quad*8 + 4 + rr
                }
                split8(v, nh[t][kb], nl[t][kb]);
            }
        }
        const int base_h = layer ? 12288 : 4096;
        const int base_l = layer ? 16384 : 8192;
        const float* __restrict__ bias = layer ? b3 : b2;
        #pragma unroll
        for (int nb = 0; nb < 4; ++nb) {
            const f32x4 bv = *(const f32x4*)(bias + nb * 16 + quad * 4);
            f32x4 c[2];
            #pragma unroll
            for (int t = 0; t < 2; ++t) c[t] = bv;
            #pragma unroll
            for (int kb = 0; kb < 2; ++kb) {
                const int idx = ((kb * 4 + nb) * 64 + lane) * 8;
                const bf16x8 wh = *(const bf16x8*)(wb + base_h + idx);
                const bf16x8 wl = *(const bf16x8*)(wb + base_l + idx);
                #pragma unroll
                for (int t = 0; t < 2; ++t) {
                    c[t] = __builtin_amdgcn_mfma_f32_16x16x32_bf16(wh, nl[t][kb], c[t], 0, 0, 0);
                    c[t] = __builtin_amdgcn_mfma_f32_16x16x32_bf16(wl, nh[t][kb], c[t], 0, 0, 0);
                    c[t] = __builtin_amdgcn_mfma_f32_16x16x32_bf16(wh, nh[t][kb], c[t], 0, 0, 0);
                }
            }
            #pragma unroll
            for (int t = 0; t < 2; ++t) acc[t][nb] = c[t];
        }
    }

    // ---- output layer: lane holds 16 neurons of point l15; quad-reduce ----
    float part[2];
    #pragma unroll
    for (int t = 0; t < 2; ++t) {
        float s = 0.f;
        #pragma unroll
        for (int nb = 0; nb < 4; ++nb) {
            const f32x4 wo4 = *(const f32x4*)(Wo + nb * 16 + quad * 4);
            #pragma unroll
            for (int r = 0; r < 4; ++r)
                s = fmaf(fmaxf(acc[t][nb][r], 0.f), wo4[r], s);
        }
        part[t] = s;
    }
    #pragma unroll
    for (int t = 0; t < 2; ++t) {
        part[t] += __shfl_xor(part[t], 16, 64);
        part[t] += __shfl_xor(part[t], 32, 64);
    }
    if (quad == 0) {
        const float b = bo[0];
        #pragma unroll
        for (int t = 0; t < 2; ++t) {
            const int po = p0 + t * 16 + l15;
            if (po < n) out[po] = part[t] + b;
        }
    }
}

// ---------------- fp32 MLP (ws-fallback path) ----------------
__global__ __launch_bounds__(256, 3)
void mlp_forward(const u32x2* __restrict__ featT,
                 const float* __restrict__ W1, const float* __restrict__ b1,
                 const float* __restrict__ W2, const float* __restrict__ b2,
                 const float* __restrict__ W3, const float* __restrict__ b3,
                 const float* __restrict__ Wo, const float* __restrict__ bo,
                 float* __restrict__ out, int n)
{
    const int p = blockIdx.x * 256 + threadIdx.x;
    if (p >= n) return;
    const v2f z2 = {0.f, 0.f};
    v2f A[32], B[32];
    #pragma unroll
    for (int jq = 0; jq < 16; ++jq) {
        const v4f b = *(const v4f*)(b1 + 4 * jq);
        A[2 * jq] = b.xy; A[2 * jq + 1] = b.zw;
    }
    #pragma unroll
    for (int l = 0; l < 16; ++l) {
        const u32x2 e = __builtin_nontemporal_load(&featT[(size_t)l * n + p]);
        union { u32 u; float f; } h0, h1, l0, l1;
        h0.u = e.x << 16; h1.u = e.x & 0xffff0000u;
        l0.u = e.y << 16; l1.u = e.y & 0xffff0000u;
        v2f f; f.x = h0.f + l0.f; f.y = h1.f + l1.f;
        const v4f* w0 = (const v4f*)(W1 + (size_t)(2 * l) * 64);
        const v4f* w1 = (const v4f*)(W1 + (size_t)(2 * l + 1) * 64);
        const v2f hh0 = {f.x, f.x}, hh1 = {f.y, f.y};
        #pragma unroll
        for (int jq = 0; jq < 16; ++jq) {
            const v4f wa = w0[jq];
            A[2 * jq]     = __builtin_elementwise_fma(hh0, wa.xy, A[2 * jq]);
            A[2 * jq + 1] = __builtin_elementwise_fma(hh0, wa.zw, A[2 * jq + 1]);
        }
        #pragma unroll
        for (int jq = 0; jq < 16; ++jq) {
            const v4f wb2 = w1[jq];
            A[2 * jq]     = __builtin_elementwise_fma(hh1, wb2.xy, A[2 * jq]);
            A[2 * jq + 1] = __builtin_elementwise_fma(hh1, wb2.zw, A[2 * jq + 1]);
        }
    }
    #pragma unroll
    for (int j = 0; j < 32; ++j) A[j] = __builtin_elementwise_max(A[j], z2);
    #pragma unroll
    for (int jq = 0; jq < 16; ++jq) {
        const v4f b = *(const v4f*)(b2 + 4 * jq);
        B[2 * jq] = b.xy; B[2 * jq + 1] = b.zw;
    }
    #pragma unroll
    for (int k = 0; k < 64; ++k) {
        const float hv = A[k >> 1][k & 1];
        const v2f h = {hv, hv};
        const v4f* w = (const v4f*)(W2 + (size_t)k * 64);
        #pragma unroll
        for (int jq = 0; jq < 16; ++jq) {
            const v4f wa = w[jq];
            B[2 * jq]     = __builtin_elementwise_fma(h, wa.xy, B[2 * jq]);
            B[2 * jq + 1] = __builtin_elementwise_fma(h, wa.zw, B[2 * jq + 1]);
        }
    }
    #pragma unroll
    for (int j = 0; j < 32; ++j) B[j] = __builtin_elementwise_max(B[j], z2);
    #pragma unroll
    for (int jq = 0; jq < 16; ++jq) {
        const v4f b = *(const v4f*)(b3 + 4 * jq);
        A[2 * jq] = b.xy; A[2 * jq + 1] = b.zw;
    }
    #pragma unroll
    for (int k = 0; k < 64; ++k) {
        const float hv = B[k >> 1][k & 1];
        const v2f h = {hv, hv};
        const v4f* w = (const v4f*)(W3 + (size_t)k * 64);
        #pragma unroll
        for (int jq = 0; jq < 16; ++jq) {
            const v4f wa = w[jq];
            A[2 * jq]     = __builtin_elementwise_fma(h, wa.xy, A[2 * jq]);
            A[2 * jq + 1] = __builtin_elementwise_fma(h, wa.zw, A[2 * jq + 1]);
        }
    }
    v2f o2 = z2;
    #pragma unroll
    for (int jq = 0; jq < 16; ++jq) {
        const v4f wa = *(const v4f*)(Wo + 4 * jq);
        o2 = __builtin_elementwise_fma(__builtin_elementwise_max(A[2 * jq], z2),     wa.xy, o2);
        o2 = __builtin_elementwise_fma(__builtin_elementwise_max(A[2 * jq + 1], z2), wa.zw, o2);
    }
    out[p] = o2.x + o2.y + bo[0];
}

// ---------------- fallback (ws too small): R1-style fused ----------------
__global__ __launch_bounds__(256, 2)
void hashpinn_fused(const float* __restrict__ x,
                    const float* __restrict__ table,
                    const float* __restrict__ W1, const float* __restrict__ b1,
                    const float* __restrict__ W2, const float* __restrict__ b2,
                    const float* __restrict__ W3, const float* __restrict__ b3,
                    const float* __restrict__ Wo, const float* __restrict__ bo,
                    float* __restrict__ out, int n, ResArr rv)
{
    const int p = blockIdx.x * 256 + threadIdx.x;
    if (p >= n) return;
    const float px = x[3*p+0], py = x[3*p+1], pz = x[3*p+2];
    float feat[32];
    #pragma unroll
    for (int l = 0; l < 16; ++l) {
        const int res = rv.r[l];
        const float rf = (float)(res - 1);
        const float fx = px*rf, fy = py*rf, fz = pz*rf;
        int ix=(int)floorf(fx), iy=(int)floorf(fy), iz=(int)floorf(fz);
        ix=min(max(ix,0),res-2); iy=min(max(iy,0),res-2); iz=min(max(iz,0),res-2);
        const float tx=fx-(float)ix, ty=fy-(float)iy, tz=fz-(float)iz;
        const float sx=1.f-tx, sy=1.f-ty, sz=1.f-tz;
        const float2* tbl=(const float2*)table+(size_t)l*HASH_SZ;
        const bool dense=((long long)res*res*res<=(long long)HASH_SZ);
        float a0=0.f, a1=0.f;
        #pragma unroll
        for (int c=0;c<8;++c){
            const uint32_t cx=(uint32_t)(ix+((c>>2)&1));
            const uint32_t cy=(uint32_t)(iy+((c>>1)&1));
            const uint32_t cz=(uint32_t)(iz+(c&1));
            uint32_t idx = dense ? cx+(uint32_t)res*(cy+(uint32_t)res*cz)
                                 : ((cx*1u ^ cy*PR2 ^ cz*PR3)&HMASK);
            const float2 v=tbl[idx];
            const float w=(((c>>2)&1)?tx:sx)*(((c>>1)&1)?ty:sy)*((c&1)?tz:sz);
            a0=fmaf(w,v.x,a0); a1=fmaf(w,v.y,a1);
        }
        feat[2*l]=a0; feat[2*l+1]=a1;
    }
    float A[64], B[64];
    #pragma unroll
    for (int j=0;j<64;++j) A[j]=b1[j];
    #pragma unroll
    for (int k=0;k<32;++k){ const float h=feat[k];
        #pragma unroll
        for (int j=0;j<64;++j) A[j]=fmaf(h,W1[k*64+j],A[j]); }
    #pragma unroll 1
    for (int it=0;it<2;++it){
        const float* W = it?W3:W2; const float* bb = it?b3:b2;
        #pragma unroll
        for (int j=0;j<64;++j){ A[j]=fmaxf(A[j],0.f); B[j]=bb[j]; }
        #pragma unroll
        for (int k=0;k<64;++k){ const float h=A[k];
            #pragma unroll
            for (int j=0;j<64;++j) B[j]=fmaf(h,W[k*64+j],B[j]); }
        #pragma unroll
        for (int j=0;j<64;++j) A[j]=B[j];
    }
    float o=bo[0];
    #pragma unroll
    for (int j=0;j<64;++j) o=fmaf(fmaxf(A[j],0.f),Wo[j],o);
    out[p]=o;
}

static inline void launch_encode16(int nlev, const float* x, const u32* tab16,
                                   u32x2* featT, int n, int lb, const ResArr& rv,
                                   hipStream_t stream) {
    const dim3 g(4096), b(256);
    switch (nlev) {
        case 1: hipLaunchKernelGGL(encode16_k<1>, g, b, 0, stream, x, tab16, featT, n, lb, rv); break;
        case 2: hipLaunchKernelGGL(encode16_k<2>, g, b, 0, stream, x, tab16, featT, n, lb, rv); break;
        case 3: hipLaunchKernelGGL(encode16_k<3>, g, b, 0, stream, x, tab16, featT, n, lb, rv); break;
        case 4: hipLaunchKernelGGL(encode16_k<4>, g, b, 0, stream, x, tab16, featT, n, lb, rv); break;
        case 5: hipLaunchKernelGGL(encode16_k<5>, g, b, 0, stream, x, tab16, featT, n, lb, rv); break;
        case 6: hipLaunchKernelGGL(encode16_k<6>, g, b, 0, stream, x, tab16, featT, n, lb, rv); break;
        case 7: hipLaunchKernelGGL(encode16_k<7>, g, b, 0, stream, x, tab16, featT, n, lb, rv); break;
        default: hipLaunchKernelGGL(encode16_k<8>, g, b, 0, stream, x, tab16, featT, n, lb, rv); break;
    }
}

static inline void launch_encode(int nlev, const float* x, const float* table,
                                 u32x2* featT, int n, int lb, const ResArr& rv,
                                 hipStream_t stream) {
    const dim3 g(4096), b(256);
    switch (nlev) {
        case 1: hipLaunchKernelGGL(encode_k<1>, g, b, 0, stream, x, table, featT, n, lb, rv); break;
        case 2: hipLaunchKernelGGL(encode_k<2>, g, b, 0, stream, x, table, featT, n, lb, rv); break;
        case 3: hipLaunchKernelGGL(encode_k<3>, g, b, 0, stream, x, table, featT, n, lb, rv); break;
        case 4: hipLaunchKernelGGL(encode_k<4>, g, b, 0, stream, x, table, featT, n, lb, rv); break;
        case 5: hipLaunchKernelGGL(encode_k<5>, g, b, 0, stream, x, table, featT, n, lb, rv); break;
        case 6: hipLaunchKernelGGL(encode_k<6>, g, b, 0, stream, x, table, featT, n, lb, rv); break;
        case 7: hipLaunchKernelGGL(encode_k<7>, g, b, 0, stream, x, table, featT, n, lb, rv); break;
        default: hipLaunchKernelGGL(encode_k<8>, g, b, 0, stream, x, table, featT, n, lb, rv); break;
    }
}

extern "C" void kernel_launch(void* const* d_in, const int* in_sizes, int n_in,
                              void* d_out, int out_size, void* d_ws, size_t ws_size,
                              hipStream_t stream) {
    const float* x     = (const float*)d_in[0];
    const float* table = (const float*)d_in[1];
    const float* W1    = (const float*)d_in[2];
    const float* b1    = (const float*)d_in[3];
    const float* W2    = (const float*)d_in[4];
    const float* b2    = (const float*)d_in[5];
    const float* W3    = (const float*)d_in[6];
    const float* b3    = (const float*)d_in[7];
    const float* Wo    = (const float*)d_in[8];
    const float* bo    = (const float*)d_in[9];
    float* out = (float*)d_out;

    const int n = in_sizes[0] / 3;

    ResArr rv;
    const double scale = std::exp2(std::log2(2048.0 / 16.0) / 15.0);
    for (int l = 0; l < 16; ++l)
        rv.r[l] = (int)std::ceil(16.0 * std::pow(scale, (double)l));

    int dense_end = 0;
    while (dense_end < 16) {
        long long r = rv.r[dense_end];
        if (r * r * r <= (long long)HASH_SZ) ++dense_end; else break;
    }
    if (dense_end > 8) dense_end = 8;

    const size_t feat_bytes = (size_t)n * 16 * sizeof(u32x2);
    const size_t wb_bytes = 20480 * sizeof(unsigned short);
    const size_t tab16_bytes = (size_t)16 * HASH_SZ * sizeof(u32);
    const int total_entries = 16 * (int)HASH_SZ;

    if (ws_size >= feat_bytes + wb_bytes + tab16_bytes) {
        // ---- fp16-table path ----
        u32x2* featT = (u32x2*)d_ws;
        unsigned short* wb = (unsigned short*)((char*)d_ws + feat_bytes);
        u32* tab16 = (u32*)((char*)d_ws + feat_bytes + wb_bytes);

        hipLaunchKernelGGL(prep_weights, dim3(1), dim3(256), 0, stream, W1, W2, W3, wb);
        hipLaunchKernelGGL(cvt_table, dim3(8192), dim3(256), 0, stream,
                           table, tab16, total_entries);

        if (dense_end > 0)
            launch_encode16(dense_end, x, tab16, featT, n, 0, rv, stream);
        for (int l = dense_end; l < 16; ++l)
            launch_encode16(1, x, tab16, featT, n, l, rv, stream);

        const int nblocks = (n + 127) / 128;   // 128 pts/block (4 waves x 32)
        hipLaunchKernelGGL(mlp_mfma, dim3(nblocks), dim3(256), 0, stream,
                           featT, wb, b1, b2, b3, Wo, bo, out, n);
    } else if (ws_size >= feat_bytes + wb_bytes) {
        u32x2* featT = (u32x2*)d_ws;
        unsigned short* wb = (unsigned short*)((char*)d_ws + feat_bytes);

        hipLaunchKernelGGL(prep_weights, dim3(1), dim3(256), 0, stream, W1, W2, W3, wb);

        if (dense_end > 0)
            launch_encode(dense_end, x, table, featT, n, 0, rv, stream);
        for (int l = dense_end; l < 16; ++l)
            launch_encode(1, x, table, featT, n, l, rv, stream);

        const int nblocks = (n + 127) / 128;
        hipLaunchKernelGGL(mlp_mfma, dim3(nblocks), dim3(256), 0, stream,
                           featT, wb, b1, b2, b3, Wo, bo, out, n);
    } else if (ws_size >= feat_bytes) {
        u32x2* featT = (u32x2*)d_ws;
        if (dense_end > 0)
            launch_encode(dense_end, x, table, featT, n, 0, rv, stream);
        for (int l = dense_end; l < 16; ++l)
            launch_encode(1, x, table, featT, n, l, rv, stream);
        hipLaunchKernelGGL(mlp_forward, dim3((n + 255) / 256), dim3(256), 0, stream,
                           featT, W1, b1, W2, b2, W3, b3, Wo, bo, out, n);
    } else {
        hipLaunchKernelGGL(hashpinn_fused, dim3((n + 255) / 256), dim3(256), 0, stream,
                           x, table, W1, b1, W2, b2, W3, b3, Wo, bo, out, n, rv);
    }
}

// Round 5
// 981.787 us; speedup vs baseline: 1.1538x; 1.0969x over previous
//
#include <hip/hip_runtime.h>
#include <hip/hip_fp16.h>
#include <cmath>
#include <cstdint>

// HashPINN R14:
//  - R13's fp16-table path never executed: ws_size < featT(256MB)+wb+tab16(32MB).
//    (Proof: total/counters/absmax bit-identical to R12.)
//  - Fix: process points in TWO HALVES, reusing a 128MB featT slab.
//    featT(128MB)+wb(40KB)+tab16(32MB) ~ 162MB -- guaranteed to fit the
//    >=256MB workspace R9-R12 already used. cvt_table runs once; per half:
//    dense encode (levels 0-4, one dispatch) + 11 hashed single-level
//    dispatches (each 2MB fp16 table = fully L2-resident per XCD) + mlp.
//  - fp16 table mechanics (now live): hashed pair needs an extra load only
//    when ix%4==3 (prob 1/4 vs 1/2) -> 6 -> 5 line-requests/point; encode is
//    MSHR-bound so time ~ requests. Table/level 4MB -> 2MB also frees L2.
//  - Encode grids sized (nh+511)/512 blocks = 8 blocks/CU exactly.
//  - mlp_mfma/prep_weights logic unchanged (stride param ns added).

#define HASH_SZ (1u << 19)
#define HMASK   (HASH_SZ - 1u)
#define PR2 2654435761u
#define PR3 805459861u

typedef float v2f __attribute__((ext_vector_type(2)));
typedef float v4f __attribute__((ext_vector_type(4)));
typedef v4f v4fu __attribute__((aligned(8)));
typedef v2f v2fu __attribute__((aligned(8)));
typedef short bf16x8 __attribute__((ext_vector_type(8)));
typedef float f32x4 __attribute__((ext_vector_type(4)));
typedef unsigned int u32;
typedef u32 u32x2 __attribute__((ext_vector_type(2)));
typedef u32 u32x4 __attribute__((ext_vector_type(4)));
typedef u32x4 u32x4u __attribute__((aligned(8)));

struct ResArr { int r[16]; };

// ---------- bf16 helpers ----------
__device__ __forceinline__ unsigned short bf16_rne(float f) {
    union { float f; unsigned u; } v; v.f = f;
    unsigned u = v.u;
    unsigned r = (u + 0x7fffu + ((u >> 16) & 1u)) >> 16;
    return (unsigned short)r;
}
__device__ __forceinline__ float bf16f(unsigned short h) {
    union { unsigned u; float f; } v; v.u = ((unsigned)h) << 16;
    return v.f;
}
// hi = TRUNCATED bf16 (cheap); lo = RNE bf16 of the exact remainder.
__device__ __forceinline__ void split8(const float* x, bf16x8& hi, bf16x8& lo) {
    #pragma unroll
    for (int j = 0; j < 8; ++j) {
        union { float f; unsigned u; } v; v.f = x[j];
        const unsigned hu = v.u & 0xffff0000u;
        hi[j] = (short)(hu >> 16);
        union { unsigned u; float f; } hf; hf.u = hu;
        const float d = x[j] - hf.f;
        union { float f; unsigned u; } dv; dv.f = d;
        lo[j] = (short)((dv.u + 0x7fffu + ((dv.u >> 16) & 1u)) >> 16);
    }
}
__device__ __forceinline__ u32 rne16u(float f) {
    union { float f; u32 u; } v; v.f = f;
    return (v.u + 0x7fffu + ((v.u >> 16) & 1u)) >> 16;
}
// pack two features into {hi0|hi1<<16, lo0|lo1<<16} (bit-identical to split8)
__device__ __forceinline__ u32x2 pack_split2(float f0, float f1) {
    union { float f; u32 u; } a, b; a.f = f0; b.f = f1;
    const u32 h0 = a.u & 0xffff0000u, h1 = b.u & 0xffff0000u;
    union { u32 u; float f; } ha, hb; ha.u = h0; hb.u = h1;
    u32x2 r;
    r.x = (h0 >> 16) | h1;
    r.y = rne16u(f0 - ha.f) | (rne16u(f1 - hb.f) << 16);
    return r;
}

// ---------- fp16 helpers ----------
__device__ __forceinline__ u32 pkh(float f0, float f1) {
    const __half h0 = __float2half_rn(f0), h1 = __float2half_rn(f1);
    return (u32)__half_as_ushort(h0) | ((u32)__half_as_ushort(h1) << 16);
}
__device__ __forceinline__ v2f cvt2(u32 e) {
    __half2 h;
    *reinterpret_cast<u32*>(&h) = e;
    v2f r; r.x = __low2float(h); r.y = __high2float(h);
    return r;
}
// select entry k (0..3) from a 16B window without runtime vector indexing
__device__ __forceinline__ u32 sel4(u32x4 P, u32 k) {
    const u32 a = (k & 1u) ? P.y : P.x;
    const u32 b = (k & 1u) ? P.w : P.z;
    return (k & 2u) ? b : a;
}

// ---------------- table conversion: fp32 pairs -> packed fp16 ----------------
__global__ __launch_bounds__(256, 8)
void cvt_table(const float* __restrict__ table, u32* __restrict__ tab16, int total)
{
    const int e0 = (blockIdx.x * 256 + threadIdx.x) * 4;
    if (e0 >= total) return;
    const v4f a = __builtin_nontemporal_load((const v4f*)(table + 2 * (size_t)e0));
    const v4f b = __builtin_nontemporal_load((const v4f*)(table + 2 * (size_t)e0 + 4));
    u32x4 o;
    o.x = pkh(a.x, a.y); o.y = pkh(a.z, a.w);
    o.z = pkh(b.x, b.y); o.w = pkh(b.z, b.w);
    *(u32x4*)(tab16 + e0) = o;
}

// ---------------- fp16-table gather ----------------
__device__ __forceinline__ void gather16_one(
    const u32* __restrict__ tab, int res, bool dense,
    float px, float py, float pz, float& A0, float& A1)
{
    const float rf = (float)(res - 1);
    const float fx = px * rf, fy = py * rf, fz = pz * rf;
    int ix = (int)floorf(fx), iy = (int)floorf(fy), iz = (int)floorf(fz);
    ix = min(max(ix, 0), res - 2);
    iy = min(max(iy, 0), res - 2);
    iz = min(max(iz, 0), res - 2);
    const float tx = fx - (float)ix, ty = fy - (float)iy, tz = fz - (float)iz;
    const float sx = 1.f - tx, sy = 1.f - ty, sz = 1.f - tz;
    float a0 = 0.f, a1 = 0.f;

    if (dense) {
        const int b0 = ix + res * (iy + res * iz);
        #pragma unroll
        for (int c = 0; c < 4; ++c) {
            const int dy = c >> 1, dz = c & 1;
            const u32 idx0 = (u32)(b0 + res * dy + res * res * dz);
            const u32x4u Pv = *(const u32x4u*)(tab + (idx0 & ~1u));
            const bool hi = (idx0 & 1u) != 0u;
            const u32 e0 = hi ? Pv.y : Pv.x;
            const u32 e1 = hi ? Pv.z : Pv.y;
            const float wyz = (dy ? ty : sy) * (dz ? tz : sz);
            const float w0 = sx * wyz, w1 = tx * wyz;
            const v2f f0 = cvt2(e0), f1 = cvt2(e1);
            a0 = fmaf(w0, f0.x, a0); a1 = fmaf(w0, f0.y, a1);
            a0 = fmaf(w1, f1.x, a0); a1 = fmaf(w1, f1.y, a1);
        }
    } else {
        u32 i1a[4], k0[4];
        u32x4 P[4];
        #pragma unroll
        for (int c = 0; c < 4; ++c) {
            const int dy = c >> 1, dz = c & 1;
            const u32 r = (u32)(iy + dy) * PR2 ^ (u32)(iz + dz) * PR3;
            const u32 i0 = ((u32)ix ^ r) & HMASK;
            i1a[c] = ((u32)(ix + 1) ^ r) & HMASK;
            k0[c] = i0 & 3u;
            P[c] = *(const u32x4*)(tab + (i0 & ~3u));
        }
        const bool extra = ((ix & 3) == 3);   // (ix^(ix+1)) spans the 4-window
        u32 O[4];
        if (extra) {
            #pragma unroll
            for (int c = 0; c < 4; ++c) O[c] = tab[i1a[c]];
        } else {
            #pragma unroll
            for (int c = 0; c < 4; ++c) O[c] = 0u;
        }
        #pragma unroll
        for (int c = 0; c < 4; ++c) {
            const int dy = c >> 1, dz = c & 1;
            const u32 e0 = sel4(P[c], k0[c]);
            const u32 e1w = sel4(P[c], i1a[c] & 3u);
            const u32 e1 = extra ? O[c] : e1w;
            const float wyz = (dy ? ty : sy) * (dz ? tz : sz);
            const float w0 = sx * wyz, w1 = tx * wyz;
            const v2f f0 = cvt2(e0), f1 = cvt2(e1);
            a0 = fmaf(w0, f0.x, a0); a1 = fmaf(w0, f0.y, a1);
            a0 = fmaf(w1, f1.x, a0); a1 = fmaf(w1, f1.y, a1);
        }
    }
    A0 = a0; A1 = a1;
}

template<int NLEV>
__global__ __launch_bounds__(256, 8)
void encode16_k(const float* __restrict__ x, const u32* __restrict__ tab16,
                u32x2* __restrict__ featT, int n, int ns, int lb, ResArr rv)
{
    const int nth2 = gridDim.x * 512;
    for (int q = (blockIdx.x * 256 + threadIdx.x) * 2; q < n; q += nth2) {
        float p0x, p0y, p0z, p1x, p1y, p1z;
        const bool two = (q + 1 < n);
        if (two) {
            const v4fu a = __builtin_nontemporal_load((const v4fu*)(x + 3 * q));
            const v2f  b = __builtin_nontemporal_load((const v2fu*)(x + 3 * q + 4));
            p0x = a.x; p0y = a.y; p0z = a.z; p1x = a.w; p1y = b.x; p1z = b.y;
        } else {
            p0x = x[3 * q]; p0y = x[3 * q + 1]; p0z = x[3 * q + 2];
            p1x = p0x; p1y = p0y; p1z = p0z;
        }
        #pragma unroll
        for (int il = 0; il < NLEV; ++il) {
            const int l = lb + il;
            const int res = rv.r[l];
            const bool dense = ((long long)res * res * res <= (long long)HASH_SZ);
            const u32* tbl = tab16 + (size_t)l * HASH_SZ;
            float a00, a01, a10, a11;
            gather16_one(tbl, res, dense, p0x, p0y, p0z, a00, a01);
            gather16_one(tbl, res, dense, p1x, p1y, p1z, a10, a11);
            if (two) {
                const u32x2 e0 = pack_split2(a00, a01);
                const u32x2 e1 = pack_split2(a10, a11);
                u32x4 st; st.x = e0.x; st.y = e0.y; st.z = e1.x; st.w = e1.y;
                __builtin_nontemporal_store(st, (u32x4*)&featT[(size_t)l * ns + q]);
            } else {
                __builtin_nontemporal_store(pack_split2(a00, a01),
                                            &featT[(size_t)l * ns + q]);
            }
        }
    }
}

// ---------------- fp32 encode (ws-fallback path) ----------------
__device__ __forceinline__ void gather_one(
    const v2f* __restrict__ tbl, int res, bool dense,
    float px, float py, float pz, float& A0, float& A1)
{
    const float rf = (float)(res - 1);
    const float fx = px * rf, fy = py * rf, fz = pz * rf;
    int ix = (int)floorf(fx), iy = (int)floorf(fy), iz = (int)floorf(fz);
    ix = min(max(ix, 0), res - 2);
    iy = min(max(iy, 0), res - 2);
    iz = min(max(iz, 0), res - 2);
    const float tx = fx - (float)ix, ty = fy - (float)iy, tz = fz - (float)iz;
    const float sx = 1.f - tx, sy = 1.f - ty, sz = 1.f - tz;
    float a0 = 0.f, a1 = 0.f;

    if (dense) {
        const int b0 = ix + res * (iy + res * iz);
        v4fu P[4];
        #pragma unroll
        for (int c = 0; c < 4; ++c) {
            const int dy = c >> 1, dz = c & 1;
            P[c] = *(const v4fu*)((const float*)tbl + 2 * (b0 + res * dy + res * res * dz));
        }
        #pragma unroll
        for (int c = 0; c < 4; ++c) {
            const int dy = c >> 1, dz = c & 1;
            const float wyz = (dy ? ty : sy) * (dz ? tz : sz);
            const float w0 = sx * wyz, w1 = tx * wyz;
            a0 = fmaf(w0, P[c].x, a0); a1 = fmaf(w0, P[c].y, a1);
            a0 = fmaf(w1, P[c].z, a0); a1 = fmaf(w1, P[c].w, a1);
        }
    } else {
        uint32_t i0[4], i1[4];
        v4f P[4];
        #pragma unroll
        for (int c = 0; c < 4; ++c) {
            const int dy = c >> 1, dz = c & 1;
            const uint32_t r = (uint32_t)(iy + dy) * PR2 ^ (uint32_t)(iz + dz) * PR3;
            i0[c] = ((uint32_t)ix ^ r) & HMASK;
            i1[c] = ((uint32_t)(ix + 1) ^ r) & HMASK;
            P[c] = *(const v4f*)((const float*)tbl + 2 * (i0[c] & ~1u));
        }
        const bool odd = (ix & 1);
        v2f O[4];
        if (odd) {
            #pragma unroll
            for (int c = 0; c < 4; ++c) O[c] = tbl[i1[c]];
        } else {
            #pragma unroll
            for (int c = 0; c < 4; ++c) { v2f z = {0.f, 0.f}; O[c] = z; }
        }
        #pragma unroll
        for (int c = 0; c < 4; ++c) {
            const int dy = c >> 1, dz = c & 1;
            const bool hi = (i0[c] & 1);
            v2f c0, e;
            c0.x = hi ? P[c].z : P[c].x;  c0.y = hi ? P[c].w : P[c].y;
            e.x  = hi ? P[c].x : P[c].z;  e.y  = hi ? P[c].y : P[c].w;
            const v2f c1 = odd ? O[c] : e;
            const float wyz = (dy ? ty : sy) * (dz ? tz : sz);
            const float w0 = sx * wyz, w1 = tx * wyz;
            a0 = fmaf(w0, c0.x, a0); a1 = fmaf(w0, c0.y, a1);
            a0 = fmaf(w1, c1.x, a0); a1 = fmaf(w1, c1.y, a1);
        }
    }
    A0 = a0; A1 = a1;
}

template<int NLEV>
__global__ __launch_bounds__(256, 8)
void encode_k(const float* __restrict__ x, const float* __restrict__ table,
              u32x2* __restrict__ featT, int n, int lb, ResArr rv)
{
    const int nth2 = gridDim.x * 512;
    for (int q = (blockIdx.x * 256 + threadIdx.x) * 2; q < n; q += nth2) {
        float p0x, p0y, p0z, p1x, p1y, p1z;
        const bool two = (q + 1 < n);
        if (two) {
            const v4fu a = __builtin_nontemporal_load((const v4fu*)(x + 3 * q));
            const v2f  b = __builtin_nontemporal_load((const v2fu*)(x + 3 * q + 4));
            p0x = a.x; p0y = a.y; p0z = a.z; p1x = a.w; p1y = b.x; p1z = b.y;
        } else {
            p0x = x[3 * q]; p0y = x[3 * q + 1]; p0z = x[3 * q + 2];
            p1x = p0x; p1y = p0y; p1z = p0z;
        }
        #pragma unroll
        for (int il = 0; il < NLEV; ++il) {
            const int l = lb + il;
            const int res = rv.r[l];
            const bool dense = ((long long)res * res * res <= (long long)HASH_SZ);
            const v2f* tbl = (const v2f*)table + (size_t)l * HASH_SZ;
            float a00, a01, a10, a11;
            gather_one(tbl, res, dense, p0x, p0y, p0z, a00, a01);
            gather_one(tbl, res, dense, p1x, p1y, p1z, a10, a11);
            if (two) {
                const u32x2 e0 = pack_split2(a00, a01);
                const u32x2 e1 = pack_split2(a10, a11);
                u32x4 st; st.x = e0.x; st.y = e0.y; st.z = e1.x; st.w = e1.y;
                __builtin_nontemporal_store(st, (u32x4*)&featT[(size_t)l * n + q]);
            } else {
                __builtin_nontemporal_store(pack_split2(a00, a01),
                                            &featT[(size_t)l * n + q]);
            }
        }
    }
}

// ---------------- weight prep (layout doubles as A-operand frags) ----------------
__global__ void prep_weights(const float* __restrict__ W1,
                             const float* __restrict__ W2,
                             const float* __restrict__ W3,
                             unsigned short* __restrict__ wb)
{
    const int tid = threadIdx.x;
    const int nb = tid >> 6, lane = tid & 63;
    const int l15 = lane & 15, q = lane >> 4;
    #pragma unroll
    for (int j = 0; j < 8; ++j) {
        const float v = W1[(q * 8 + j) * 64 + nb * 16 + l15];
        const unsigned short h = bf16_rne(v);
        wb[(nb * 64 + lane) * 8 + j] = h;
        wb[2048 + (nb * 64 + lane) * 8 + j] = bf16_rne(v - bf16f(h));
    }
    #pragma unroll
    for (int kb = 0; kb < 2; ++kb) {
        #pragma unroll
        for (int j = 0; j < 8; ++j) {
            const int row = kb * 32 + q * 8 + j;
            const int idx = ((kb * 4 + nb) * 64 + lane) * 8 + j;
            float v = W2[row * 64 + nb * 16 + l15];
            unsigned short h = bf16_rne(v);
            wb[4096 + idx] = h;
            wb[8192 + idx] = bf16_rne(v - bf16f(h));
            v = W3[row * 64 + nb * 16 + l15];
            h = bf16_rne(v);
            wb[12288 + idx] = h;
            wb[16384 + idx] = bf16_rne(v - bf16f(h));
        }
    }
}

// ---------------- MFMA MLP: weights=A, acts=B, no LDS, permlane exchange ----------------
__global__ __launch_bounds__(256, 4)
void mlp_mfma(const u32x2* __restrict__ featT,
              const unsigned short* __restrict__ wb,
              const float* __restrict__ b1, const float* __restrict__ b2,
              const float* __restrict__ b3,
              const float* __restrict__ Wo, const float* __restrict__ bo,
              float* __restrict__ out, int n, int ns)
{
    const int wave = threadIdx.x >> 6;
    const int lane = threadIdx.x & 63;
    const int l15 = lane & 15, quad = lane >> 4;
    const int p0 = (blockIdx.x * 4 + wave) * 32;
    if (p0 >= n) return;

    // ---- layer 1: B-frags straight from pre-split featT ----
    bf16x8 bh[2], bl[2];
    #pragma unroll
    for (int t = 0; t < 2; ++t) {
        const int p = p0 + t * 16 + l15;
        const int pl = (p < n) ? p : (n - 1);
        u32x4 hw, lw;
        #pragma unroll
        for (int jj = 0; jj < 4; ++jj) {
            const u32x2 v = featT[(size_t)(quad * 4 + jj) * ns + pl];
            hw[jj] = v.x; lw[jj] = v.y;
        }
        bh[t] = *(bf16x8*)&hw;
        bl[t] = *(bf16x8*)&lw;
    }

    f32x4 acc[2][4];
    #pragma unroll
    for (int nb = 0; nb < 4; ++nb) {
        const bf16x8 wh = *(const bf16x8*)(wb + (nb * 64 + lane) * 8);
        const bf16x8 wl = *(const bf16x8*)(wb + 2048 + (nb * 64 + lane) * 8);
        const f32x4 bv = *(const f32x4*)(b1 + nb * 16 + quad * 4);
        #pragma unroll
        for (int t = 0; t < 2; ++t) {
            f32x4 c = bv;
            c = __builtin_amdgcn_mfma_f32_16x16x32_bf16(wh, bl[t], c, 0, 0, 0);
            c = __builtin_amdgcn_mfma_f32_16x16x32_bf16(wl, bh[t], c, 0, 0, 0);
            c = __builtin_amdgcn_mfma_f32_16x16x32_bf16(wh, bh[t], c, 0, 0, 0);
            acc[t][nb] = c;
        }
    }

    // ---- hidden layers 2 & 3 ----
    #pragma unroll
    for (int layer = 0; layer < 2; ++layer) {
        // C-layout -> B-frag layout, pure VALU.
        // swap32(dst=x,src=y): x={xq0,xq1|yq0,yq1}, y={xq2,xq3|yq2,yq3}
        // swap16(dst=x,src=y): x={xq0,xq2,yq0,yq2}=v[r], y={xq1,xq3,yq1,yq3}=v[4+r]
        bf16x8 nh[2][2], nl[2][2];
        #pragma unroll
        for (int t = 0; t < 2; ++t) {
            #pragma unroll
            for (int kb = 0; kb < 2; ++kb) {
                float v[8];
                #pragma unroll
                for (int rr = 0; rr < 4; ++rr) {
                    float xq = fmaxf(acc[t][2 * kb][rr],     0.f);
                    float yq = fmaxf(acc[t][2 * kb + 1][rr], 0.f);
                    asm("v_permlane32_swap_b32 %0, %1" : "+v"(xq), "+v"(yq));
                    asm("v_permlane16_swap_b32 %0, %1" : "+v"(xq), "+v"(yq));
                    v[rr]     = xq;   // k = quad*8 + rr
                    v[4 + rr] = yq;   // k = quad*8 + 4 + rr
                }
                split8(v, nh[t][kb], nl[t][kb]);
            }
        }
        const int base_h = layer ? 12288 : 4096;
        const int base_l = layer ? 16384 : 8192;
        const float* __restrict__ bias = layer ? b3 : b2;
        #pragma unroll
        for (int nb = 0; nb < 4; ++nb) {
            const f32x4 bv = *(const f32x4*)(bias + nb * 16 + quad * 4);
            f32x4 c[2];
            #pragma unroll
            for (int t = 0; t < 2; ++t) c[t] = bv;
            #pragma unroll
            for (int kb = 0; kb < 2; ++kb) {
                const int idx = ((kb * 4 + nb) * 64 + lane) * 8;
                const bf16x8 wh = *(const bf16x8*)(wb + base_h + idx);
                const bf16x8 wl = *(const bf16x8*)(wb + base_l + idx);
                #pragma unroll
                for (int t = 0; t < 2; ++t) {
                    c[t] = __builtin_amdgcn_mfma_f32_16x16x32_bf16(wh, nl[t][kb], c[t], 0, 0, 0);
                    c[t] = __builtin_amdgcn_mfma_f32_16x16x32_bf16(wl, nh[t][kb], c[t], 0, 0, 0);
                    c[t] = __builtin_amdgcn_mfma_f32_16x16x32_bf16(wh, nh[t][kb], c[t], 0, 0, 0);
                }
            }
            #pragma unroll
            for (int t = 0; t < 2; ++t) acc[t][nb] = c[t];
        }
    }

    // ---- output layer: lane holds 16 neurons of point l15; quad-reduce ----
    float part[2];
    #pragma unroll
    for (int t = 0; t < 2; ++t) {
        float s = 0.f;
        #pragma unroll
        for (int nb = 0; nb < 4; ++nb) {
            const f32x4 wo4 = *(const f32x4*)(Wo + nb * 16 + quad * 4);
            #pragma unroll
            for (int r = 0; r < 4; ++r)
                s = fmaf(fmaxf(acc[t][nb][r], 0.f), wo4[r], s);
        }
        part[t] = s;
    }
    #pragma unroll
    for (int t = 0; t < 2; ++t) {
        part[t] += __shfl_xor(part[t], 16, 64);
        part[t] += __shfl_xor(part[t], 32, 64);
    }
    if (quad == 0) {
        const float b = bo[0];
        #pragma unroll
        for (int t = 0; t < 2; ++t) {
            const int po = p0 + t * 16 + l15;
            if (po < n) out[po] = part[t] + b;
        }
    }
}

// ---------------- fp32 MLP (ws-fallback path) ----------------
__global__ __launch_bounds__(256, 3)
void mlp_forward(const u32x2* __restrict__ featT,
                 const float* __restrict__ W1, const float* __restrict__ b1,
                 const float* __restrict__ W2, const float* __restrict__ b2,
                 const float* __restrict__ W3, const float* __restrict__ b3,
                 const float* __restrict__ Wo, const float* __restrict__ bo,
                 float* __restrict__ out, int n)
{
    const int p = blockIdx.x * 256 + threadIdx.x;
    if (p >= n) return;
    const v2f z2 = {0.f, 0.f};
    v2f A[32], B[32];
    #pragma unroll
    for (int jq = 0; jq < 16; ++jq) {
        const v4f b = *(const v4f*)(b1 + 4 * jq);
        A[2 * jq] = b.xy; A[2 * jq + 1] = b.zw;
    }
    #pragma unroll
    for (int l = 0; l < 16; ++l) {
        const u32x2 e = __builtin_nontemporal_load(&featT[(size_t)l * n + p]);
        union { u32 u; float f; } h0, h1, l0, l1;
        h0.u = e.x << 16; h1.u = e.x & 0xffff0000u;
        l0.u = e.y << 16; l1.u = e.y & 0xffff0000u;
        v2f f; f.x = h0.f + l0.f; f.y = h1.f + l1.f;
        const v4f* w0 = (const v4f*)(W1 + (size_t)(2 * l) * 64);
        const v4f* w1 = (const v4f*)(W1 + (size_t)(2 * l + 1) * 64);
        const v2f hh0 = {f.x, f.x}, hh1 = {f.y, f.y};
        #pragma unroll
        for (int jq = 0; jq < 16; ++jq) {
            const v4f wa = w0[jq];
            A[2 * jq]     = __builtin_elementwise_fma(hh0, wa.xy, A[2 * jq]);
            A[2 * jq + 1] = __builtin_elementwise_fma(hh0, wa.zw, A[2 * jq + 1]);
        }
        #pragma unroll
        for (int jq = 0; jq < 16; ++jq) {
            const v4f wb2 = w1[jq];
            A[2 * jq]     = __builtin_elementwise_fma(hh1, wb2.xy, A[2 * jq]);
            A[2 * jq + 1] = __builtin_elementwise_fma(hh1, wb2.zw, A[2 * jq + 1]);
        }
    }
    #pragma unroll
    for (int j = 0; j < 32; ++j) A[j] = __builtin_elementwise_max(A[j], z2);
    #pragma unroll
    for (int jq = 0; jq < 16; ++jq) {
        const v4f b = *(const v4f*)(b2 + 4 * jq);
        B[2 * jq] = b.xy; B[2 * jq + 1] = b.zw;
    }
    #pragma unroll
    for (int k = 0; k < 64; ++k) {
        const float hv = A[k >> 1][k & 1];
        const v2f h = {hv, hv};
        const v4f* w = (const v4f*)(W2 + (size_t)k * 64);
        #pragma unroll
        for (int jq = 0; jq < 16; ++jq) {
            const v4f wa = w[jq];
            B[2 * jq]     = __builtin_elementwise_fma(h, wa.xy, B[2 * jq]);
            B[2 * jq + 1] = __builtin_elementwise_fma(h, wa.zw, B[2 * jq + 1]);
        }
    }
    #pragma unroll
    for (int j = 0; j < 32; ++j) B[j] = __builtin_elementwise_max(B[j], z2);
    #pragma unroll
    for (int jq = 0; jq < 16; ++jq) {
        const v4f b = *(const v4f*)(b3 + 4 * jq);
        A[2 * jq] = b.xy; A[2 * jq + 1] = b.zw;
    }
    #pragma unroll
    for (int k = 0; k < 64; ++k) {
        const float hv = B[k >> 1][k & 1];
        const v2f h = {hv, hv};
        const v4f* w = (const v4f*)(W3 + (size_t)k * 64);
        #pragma unroll
        for (int jq = 0; jq < 16; ++jq) {
            const v4f wa = w[jq];
            A[2 * jq]     = __builtin_elementwise_fma(h, wa.xy, A[2 * jq]);
            A[2 * jq + 1] = __builtin_elementwise_fma(h, wa.zw, A[2 * jq + 1]);
        }
    }
    v2f o2 = z2;
    #pragma unroll
    for (int jq = 0; jq < 16; ++jq) {
        const v4f wa = *(const v4f*)(Wo + 4 * jq);
        o2 = __builtin_elementwise_fma(__builtin_elementwise_max(A[2 * jq], z2),     wa.xy, o2);
        o2 = __builtin_elementwise_fma(__builtin_elementwise_max(A[2 * jq + 1], z2), wa.zw, o2);
    }
    out[p] = o2.x + o2.y + bo[0];
}

// ---------------- fallback (ws too small): R1-style fused ----------------
__global__ __launch_bounds__(256, 2)
void hashpinn_fused(const float* __restrict__ x,
                    const float* __restrict__ table,
                    const float* __restrict__ W1, const float* __restrict__ b1,
                    const float* __restrict__ W2, const float* __restrict__ b2,
                    const float* __restrict__ W3, const float* __restrict__ b3,
                    const float* __restrict__ Wo, const float* __restrict__ bo,
                    float* __restrict__ out, int n, ResArr rv)
{
    const int p = blockIdx.x * 256 + threadIdx.x;
    if (p >= n) return;
    const float px = x[3*p+0], py = x[3*p+1], pz = x[3*p+2];
    float feat[32];
    #pragma unroll
    for (int l = 0; l < 16; ++l) {
        const int res = rv.r[l];
        const float rf = (float)(res - 1);
        const float fx = px*rf, fy = py*rf, fz = pz*rf;
        int ix=(int)floorf(fx), iy=(int)floorf(fy), iz=(int)floorf(fz);
        ix=min(max(ix,0),res-2); iy=min(max(iy,0),res-2); iz=min(max(iz,0),res-2);
        const float tx=fx-(float)ix, ty=fy-(float)iy, tz=fz-(float)iz;
        const float sx=1.f-tx, sy=1.f-ty, sz=1.f-tz;
        const float2* tbl=(const float2*)table+(size_t)l*HASH_SZ;
        const bool dense=((long long)res*res*res<=(long long)HASH_SZ);
        float a0=0.f, a1=0.f;
        #pragma unroll
        for (int c=0;c<8;++c){
            const uint32_t cx=(uint32_t)(ix+((c>>2)&1));
            const uint32_t cy=(uint32_t)(iy+((c>>1)&1));
            const uint32_t cz=(uint32_t)(iz+(c&1));
            uint32_t idx = dense ? cx+(uint32_t)res*(cy+(uint32_t)res*cz)
                                 : ((cx*1u ^ cy*PR2 ^ cz*PR3)&HMASK);
            const float2 v=tbl[idx];
            const float w=(((c>>2)&1)?tx:sx)*(((c>>1)&1)?ty:sy)*((c&1)?tz:sz);
            a0=fmaf(w,v.x,a0); a1=fmaf(w,v.y,a1);
        }
        feat[2*l]=a0; feat[2*l+1]=a1;
    }
    float A[64], B[64];
    #pragma unroll
    for (int j=0;j<64;++j) A[j]=b1[j];
    #pragma unroll
    for (int k=0;k<32;++k){ const float h=feat[k];
        #pragma unroll
        for (int j=0;j<64;++j) A[j]=fmaf(h,W1[k*64+j],A[j]); }
    #pragma unroll 1
    for (int it=0;it<2;++it){
        const float* W = it?W3:W2; const float* bb = it?b3:b2;
        #pragma unroll
        for (int j=0;j<64;++j){ A[j]=fmaxf(A[j],0.f); B[j]=bb[j]; }
        #pragma unroll
        for (int k=0;k<64;++k){ const float h=A[k];
            #pragma unroll
            for (int j=0;j<64;++j) B[j]=fmaf(h,W[k*64+j],B[j]); }
        #pragma unroll
        for (int j=0;j<64;++j) A[j]=B[j];
    }
    float o=bo[0];
    #pragma unroll
    for (int j=0;j<64;++j) o=fmaf(fmaxf(A[j],0.f),Wo[j],o);
    out[p]=o;
}

static inline void launch_encode16(int nlev, const float* x, const u32* tab16,
                                   u32x2* featT, int n, int ns, int lb,
                                   const ResArr& rv, hipStream_t stream) {
    const dim3 g((n + 511) / 512), b(256);
    switch (nlev) {
        case 1: hipLaunchKernelGGL(encode16_k<1>, g, b, 0, stream, x, tab16, featT, n, ns, lb, rv); break;
        case 2: hipLaunchKernelGGL(encode16_k<2>, g, b, 0, stream, x, tab16, featT, n, ns, lb, rv); break;
        case 3: hipLaunchKernelGGL(encode16_k<3>, g, b, 0, stream, x, tab16, featT, n, ns, lb, rv); break;
        case 4: hipLaunchKernelGGL(encode16_k<4>, g, b, 0, stream, x, tab16, featT, n, ns, lb, rv); break;
        case 5: hipLaunchKernelGGL(encode16_k<5>, g, b, 0, stream, x, tab16, featT, n, ns, lb, rv); break;
        case 6: hipLaunchKernelGGL(encode16_k<6>, g, b, 0, stream, x, tab16, featT, n, ns, lb, rv); break;
        case 7: hipLaunchKernelGGL(encode16_k<7>, g, b, 0, stream, x, tab16, featT, n, ns, lb, rv); break;
        default: hipLaunchKernelGGL(encode16_k<8>, g, b, 0, stream, x, tab16, featT, n, ns, lb, rv); break;
    }
}

static inline void launch_encode(int nlev, const float* x, const float* table,
                                 u32x2* featT, int n, int lb, const ResArr& rv,
                                 hipStream_t stream) {
    const dim3 g(4096), b(256);
    switch (nlev) {
        case 1: hipLaunchKernelGGL(encode_k<1>, g, b, 0, stream, x, table, featT, n, lb, rv); break;
        case 2: hipLaunchKernelGGL(encode_k<2>, g, b, 0, stream, x, table, featT, n, lb, rv); break;
        case 3: hipLaunchKernelGGL(encode_k<3>, g, b, 0, stream, x, table, featT, n, lb, rv); break;
        case 4: hipLaunchKernelGGL(encode_k<4>, g, b, 0, stream, x, table, featT, n, lb, rv); break;
        case 5: hipLaunchKernelGGL(encode_k<5>, g, b, 0, stream, x, table, featT, n, lb, rv); break;
        case 6: hipLaunchKernelGGL(encode_k<6>, g, b, 0, stream, x, table, featT, n, lb, rv); break;
        case 7: hipLaunchKernelGGL(encode_k<7>, g, b, 0, stream, x, table, featT, n, lb, rv); break;
        default: hipLaunchKernelGGL(encode_k<8>, g, b, 0, stream, x, table, featT, n, lb, rv); break;
    }
}

extern "C" void kernel_launch(void* const* d_in, const int* in_sizes, int n_in,
                              void* d_out, int out_size, void* d_ws, size_t ws_size,
                              hipStream_t stream) {
    const float* x     = (const float*)d_in[0];
    const float* table = (const float*)d_in[1];
    const float* W1    = (const float*)d_in[2];
    const float* b1    = (const float*)d_in[3];
    const float* W2    = (const float*)d_in[4];
    const float* b2    = (const float*)d_in[5];
    const float* W3    = (const float*)d_in[6];
    const float* b3    = (const float*)d_in[7];
    const float* Wo    = (const float*)d_in[8];
    const float* bo    = (const float*)d_in[9];
    float* out = (float*)d_out;

    const int n = in_sizes[0] / 3;

    ResArr rv;
    const double scale = std::exp2(std::log2(2048.0 / 16.0) / 15.0);
    for (int l = 0; l < 16; ++l)
        rv.r[l] = (int)std::ceil(16.0 * std::pow(scale, (double)l));

    int dense_end = 0;
    while (dense_end < 16) {
        long long r = rv.r[dense_end];
        if (r * r * r <= (long long)HASH_SZ) ++dense_end; else break;
    }
    if (dense_end > 8) dense_end = 8;

    const size_t wb_bytes = 20480 * sizeof(unsigned short);
    const size_t tab16_bytes = (size_t)16 * HASH_SZ * sizeof(u32);
    const int total_entries = 16 * (int)HASH_SZ;

    // ---- two-half fp16 path: featT sized for the larger half ----
    int h0 = ((n + 1) / 2 + 1) & ~1;     // first half, even for x/featT alignment
    if (h0 > n) h0 = n;
    const int h1 = n - h0;
    const int ns0 = (h0 + 1) & ~1;
    const int ns1 = (h1 + 1) & ~1;
    const int nsmax = ns0 > ns1 ? ns0 : ns1;
    const size_t feat_half_bytes = (size_t)nsmax * 16 * sizeof(u32x2);

    const size_t feat_bytes = (size_t)n * 16 * sizeof(u32x2);   // full (fallbacks)

    if (ws_size >= feat_half_bytes + wb_bytes + tab16_bytes) {
        u32x2* featT = (u32x2*)d_ws;
        unsigned short* wb = (unsigned short*)((char*)d_ws + feat_half_bytes);
        u32* tab16 = (u32*)((char*)d_ws + feat_half_bytes + wb_bytes);

        hipLaunchKernelGGL(prep_weights, dim3(1), dim3(256), 0, stream, W1, W2, W3, wb);
        hipLaunchKernelGGL(cvt_table, dim3(8192), dim3(256), 0, stream,
                           table, tab16, total_entries);

        #pragma unroll
        for (int half = 0; half < 2; ++half) {
            const int off = half ? h0 : 0;
            const int nh  = half ? h1 : h0;
            const int ns  = half ? ns1 : ns0;
            if (nh <= 0) continue;
            const float* xh = x + (size_t)3 * off;

            if (dense_end > 0)
                launch_encode16(dense_end, xh, tab16, featT, nh, ns, 0, rv, stream);
            for (int l = dense_end; l < 16; ++l)
                launch_encode16(1, xh, tab16, featT, nh, ns, l, rv, stream);

            const int nblocks = (nh + 127) / 128;   // 128 pts/block (4 waves x 32)
            hipLaunchKernelGGL(mlp_mfma, dim3(nblocks), dim3(256), 0, stream,
                               featT, wb, b1, b2, b3, Wo, bo, out + off, nh, ns);
        }
    } else if (ws_size >= feat_bytes + wb_bytes) {
        // ---- fallback: full fp32 featT + MFMA mlp (R12 path) ----
        u32x2* featT = (u32x2*)d_ws;
        unsigned short* wb = (unsigned short*)((char*)d_ws + feat_bytes);

        hipLaunchKernelGGL(prep_weights, dim3(1), dim3(256), 0, stream, W1, W2, W3, wb);

        if (dense_end > 0)
            launch_encode(dense_end, x, table, featT, n, 0, rv, stream);
        for (int l = dense_end; l < 16; ++l)
            launch_encode(1, x, table, featT, n, l, rv, stream);

        const int nblocks = (n + 127) / 128;
        hipLaunchKernelGGL(mlp_mfma, dim3(nblocks), dim3(256), 0, stream,
                           featT, wb, b1, b2, b3, Wo, bo, out, n, n);
    } else if (ws_size >= feat_bytes) {
        u32x2* featT = (u32x2*)d_ws;
        if (dense_end > 0)
            launch_encode(dense_end, x, table, featT, n, 0, rv, stream);
        for (int l = dense_end; l < 16; ++l)
            launch_encode(1, x, table, featT, n, l, rv, stream);
        hipLaunchKernelGGL(mlp_forward, dim3((n + 255) / 256), dim3(256), 0, stream,
                           featT, W1, b1, W2, b2, W3, b3, Wo, bo, out, n);
    } else {
        hipLaunchKernelGGL(hashpinn_fused, dim3((n + 255) / 256), dim3(256), 0, stream,
                           x, table, W1, b1, W2, b2, W3, b3, Wo, bo, out, n, rv);
    }
}